// Round 6
// baseline (477.800 us; speedup 1.0000x reference)
//
#include <hip/hip_runtime.h>
#include <hip/hip_bf16.h>

constexpr int N_NODES = 100000;
constexpr int N_EDGES = 1600000;
constexpr int D = 128;
constexpr int N_CLASSES = 64;

constexpr int PART_NODES = 32;                 // nodes per partition
constexpr int NPART = N_NODES / PART_NODES;    // 3125 (exact)
constexpr int NCTR = NPART * 8;                // 25000 (8 shards)
constexpr int CAP = 2048;                      // per-bucket edge capacity (mean 512)

typedef __attribute__((ext_vector_type(8))) short short8;
typedef __attribute__((ext_vector_type(4))) float f32x4;

static __device__ __forceinline__ float bf2f(unsigned int lo16) {
    unsigned int x = lo16 << 16;
    return __builtin_bit_cast(float, x);
}
static __device__ __forceinline__ unsigned short f2bf(float f) {
    unsigned int x = __builtin_bit_cast(unsigned int, f);
    x += 0x7fffu + ((x >> 16) & 1u);          // RNE
    return (unsigned short)(x >> 16);
}

// shard for edge e — MUST be identical in hist_k and bin_k
static __device__ __forceinline__ int shard_of(int e) { return (e >> 8) & 7; }

// ---------------------------------------------------------------------------
// 1) histogram edges into (partition, shard) buckets — 4 edges/thread
// ---------------------------------------------------------------------------
__global__ __launch_bounds__(256) void hist_k(const int* __restrict__ dst,
                                              int* __restrict__ hist) {
    int q = blockIdx.x * 256 + threadIdx.x;
    int e0 = q * 4;
    if (e0 >= N_EDGES) return;
    int sh = shard_of(e0);                     // same for e0..e0+3
    int4 d = *(const int4*)(dst + e0);
    atomicAdd(hist + (((d.x >> 5) << 3) | sh), 1);
    atomicAdd(hist + (((d.y >> 5) << 3) | sh), 1);
    atomicAdd(hist + (((d.z >> 5) << 3) | sh), 1);
    atomicAdd(hist + (((d.w >> 5) << 3) | sh), 1);
}

// ---------------------------------------------------------------------------
// 2) exclusive scan of the 25000 bucket counts (single block)
// ---------------------------------------------------------------------------
__global__ __launch_bounds__(1024) void scan_k(const int* __restrict__ hist,
                                               int* __restrict__ segbase,
                                               int* __restrict__ cursor) {
    __shared__ int part[1024];
    const int t = threadIdx.x;
    const int CH = (NCTR + 1023) / 1024;       // 25
    int s = 0;
    for (int i = 0; i < CH; ++i) {
        int idx = t * CH + i;
        if (idx < NCTR) s += hist[idx];
    }
    part[t] = s;
    __syncthreads();
    for (int off = 1; off < 1024; off <<= 1) {
        int v = (t >= off) ? part[t - off] : 0;
        __syncthreads();
        part[t] += v;
        __syncthreads();
    }
    int base = (t == 0) ? 0 : part[t - 1];
    for (int i = 0; i < CH; ++i) {
        int idx = t * CH + i;
        if (idx < NCTR) {
            segbase[idx] = base;
            cursor[idx]  = base;
            base += hist[idx];
        }
    }
    if (t == 1023) segbase[NCTR] = base;       // == N_EDGES
}

// ---------------------------------------------------------------------------
// 3) bin: append packed (dst_local<<17 | src) — 4 edges/thread, int4 loads
// ---------------------------------------------------------------------------
__global__ __launch_bounds__(256) void bin_k(const int* __restrict__ src,
                                             const int* __restrict__ dst,
                                             int* __restrict__ cursor,
                                             unsigned int* __restrict__ pack) {
    int q = blockIdx.x * 256 + threadIdx.x;
    int e0 = q * 4;
    if (e0 >= N_EDGES) return;
    int sh = shard_of(e0);
    int4 d = *(const int4*)(dst + e0);
    int4 s = *(const int4*)(src + e0);
    int p0, p1, p2, p3;
    p0 = atomicAdd(cursor + (((d.x >> 5) << 3) | sh), 1);
    p1 = atomicAdd(cursor + (((d.y >> 5) << 3) | sh), 1);
    p2 = atomicAdd(cursor + (((d.z >> 5) << 3) | sh), 1);
    p3 = atomicAdd(cursor + (((d.w >> 5) << 3) | sh), 1);
    pack[p0] = ((unsigned int)(d.x & 31) << 17) | (unsigned int)s.x;
    pack[p1] = ((unsigned int)(d.y & 31) << 17) | (unsigned int)s.y;
    pack[p2] = ((unsigned int)(d.z & 31) << 17) | (unsigned int)s.z;
    pack[p3] = ((unsigned int)(d.w & 31) << 17) | (unsigned int)s.w;
}

// ---------------------------------------------------------------------------
// feat fp32 -> bf16 into xcat1 self half (cols 0..127 of 256-wide rows)
// ---------------------------------------------------------------------------
__global__ __launch_bounds__(256) void cvt_feat_k(const float* __restrict__ feat,
                                                  unsigned short* __restrict__ xcat) {
    int i = blockIdx.x * 256 + threadIdx.x;    // float4 chunks, 3.2M total
    if (i >= N_NODES * (D / 4)) return;
    float4 v = ((const float4*)feat)[i];
    ushort4 r;
    r.x = f2bf(v.x); r.y = f2bf(v.y); r.z = f2bf(v.z); r.w = f2bf(v.w);
    int node = i >> 5;
    int c = i & 31;
    *(ushort4*)(xcat + (size_t)node * 256 + c * 4) = r;
}

// ---------------------------------------------------------------------------
// pack W (fp32, rows 0..127 from Wa, 128.. from Wb) into MFMA B-fragment order
// ---------------------------------------------------------------------------
template <int K_TOT, int DOUT>
__global__ __launch_bounds__(64) void packW_k(const float* __restrict__ Wa,
                                              const float* __restrict__ Wb,
                                              unsigned short* __restrict__ wp) {
    constexpr int NCT = DOUT / 16;
    int kstep = blockIdx.x / NCT;
    int ct = blockIdx.x % NCT;
    int lane = threadIdx.x;
    int col = ct * 16 + (lane & 15);
    int kbase = kstep * 32 + (lane >> 4) * 8;
    unsigned short r[8];
    #pragma unroll
    for (int j = 0; j < 8; ++j) {
        int k = kbase + j;
        float w = (k < 128) ? Wa[(size_t)k * DOUT + col]
                            : Wb[(size_t)(k - 128) * DOUT + col];
        r[j] = f2bf(w);
    }
    *(short8*)(wp + ((size_t)((kstep * NCT + ct) * 64 + lane)) * 8) =
        *(const short8*)r;
}

// ---------------------------------------------------------------------------
// 4) gather+mean: one block per partition.
//    a) stage bucket edges in LDS + 32-bin counting sort by dst_local,
//    b) register accumulation, 16 B/lane loads: 16 lanes cover a 256 B row,
//       so ONE dwordx4 instruction fetches 4 edges' worth per wave,
//    c) 2-hop shfl_xor fold of the 4 edge-subgroups, coalesced bf16 write.
// ---------------------------------------------------------------------------
__global__ __launch_bounds__(256) void gather_k(const unsigned short* __restrict__ xin,
                                                const unsigned int* __restrict__ pack,
                                                const int* __restrict__ segbase,
                                                unsigned short* __restrict__ xout) {
    __shared__ unsigned int eraw[CAP];
    __shared__ unsigned int ssrc[CAP];
    __shared__ int bcnt[32];
    __shared__ int boff[33];

    const int t = threadIdx.x;
    const int p = blockIdx.x;
    const int beg = segbase[p << 3];
    const int end = segbase[(p + 1) << 3];
    const int n = (end - beg) < CAP ? (end - beg) : CAP;

    if (t < 32) bcnt[t] = 0;
    __syncthreads();

    // stage + per-node histogram
    for (int i = t; i < n; i += 256) {
        unsigned int pk = pack[beg + i];
        eraw[i] = pk;
        atomicAdd(&bcnt[pk >> 17], 1);
    }
    __syncthreads();

    // tiny serial scan (32 bins)
    if (t == 0) {
        int s = 0;
        #pragma unroll
        for (int i = 0; i < 32; ++i) { boff[i] = s; s += bcnt[i]; }
        boff[32] = s;
    }
    __syncthreads();
    if (t < 32) bcnt[t] = boff[t];             // reuse as cursor
    __syncthreads();

    // scatter into per-node-sorted order
    for (int i = t; i < n; i += 256) {
        unsigned int pk = eraw[i];
        int pos = atomicAdd(&bcnt[pk >> 17], 1);
        ssrc[pos] = pk & 0x1ffffu;
    }
    __syncthreads();

    // register accumulation: wave w -> nodes w*8 .. w*8+7
    // lane = sub*16 + cl : sub = edge slot (0..3), cl = column group (cols cl*8..+7)
    const int w = t >> 6, lane = t & 63;
    const int sub = lane >> 4;
    const int cl = lane & 15;
    const int nodeb = p * PART_NODES;

    for (int g = 0; g < 8; ++g) {
        const int ni = w * 8 + g;
        const int b = boff[ni];
        const int eN = boff[ni + 1];

        float acc[8];
        #pragma unroll
        for (int r = 0; r < 8; ++r) acc[r] = 0.f;

        for (int i = b + sub; i < eN; i += 4) {
            int s = ssrc[i];
            uint4 u = *(const uint4*)(xin + (size_t)s * 256 + cl * 8);
            acc[0] += bf2f(u.x & 0xffffu); acc[1] += bf2f(u.x >> 16);
            acc[2] += bf2f(u.y & 0xffffu); acc[3] += bf2f(u.y >> 16);
            acc[4] += bf2f(u.z & 0xffffu); acc[5] += bf2f(u.z >> 16);
            acc[6] += bf2f(u.w & 0xffffu); acc[7] += bf2f(u.w >> 16);
        }

        // fold the 4 edge-subgroups (lanes differing in bits 4,5)
        #pragma unroll
        for (int r = 0; r < 8; ++r) {
            acc[r] += __shfl_xor(acc[r], 16);
            acc[r] += __shfl_xor(acc[r], 32);
        }

        float inv = 1.0f / fmaxf((float)(eN - b), 1.0f);
        // lane writes the uint covering cols cl*8 + sub*2 .. +1
        float lo = acc[sub * 2 + 0] * inv;
        float hi = acc[sub * 2 + 1] * inv;
        unsigned int o = ((unsigned int)f2bf(hi) << 16) | (unsigned int)f2bf(lo);
        *(unsigned int*)(xout + (size_t)(nodeb + ni) * 256 + 128 + cl * 8 + sub * 2) = o;
    }
}

// ---------------------------------------------------------------------------
// MFMA GEMM: C = act(A @ W + b). W staged in LDS once per block; 4 waves,
// 32 rows/wave (two 16-row A-fragments share each B-fragment).
// ---------------------------------------------------------------------------
template <int K_TOT, int DOUT, bool RELU, bool BF16OUT>
__global__ __launch_bounds__(256) void gemm_k(const unsigned short* __restrict__ A,
                                              int lda,
                                              const short8* __restrict__ Wp,
                                              const float* __restrict__ bias,
                                              void* __restrict__ Cout, int ldc) {
    constexpr int NCT = DOUT / 16;
    constexpr int KST = K_TOT / 32;
    constexpr int NW8 = KST * NCT * 64;        // 4096 (64KB) or 1024 (16KB)
    __shared__ short8 wl[NW8];
    const int t = threadIdx.x;
    #pragma unroll
    for (int i = 0; i < NW8 / 256; ++i) wl[t + i * 256] = Wp[t + i * 256];
    __syncthreads();

    const int wid = t >> 6, lane = t & 63;
    const int row0 = blockIdx.x * 128 + wid * 32;
    if (row0 + 16 > N_NODES) return;
    const bool ok1 = (row0 + 32 <= N_NODES);

    const unsigned short* ar0 =
        A + (size_t)(row0 + (lane & 15)) * lda + (lane >> 4) * 8;
    const unsigned short* ar1 = ar0 + (size_t)16 * lda;

    f32x4 acc0[NCT], acc1[NCT];
    #pragma unroll
    for (int ct = 0; ct < NCT; ++ct) {
        acc0[ct] = {0.f, 0.f, 0.f, 0.f};
        acc1[ct] = {0.f, 0.f, 0.f, 0.f};
    }

    #pragma unroll
    for (int ks = 0; ks < KST; ++ks) {
        short8 a0 = *(const short8*)(ar0 + ks * 32);
        short8 a1 = {0, 0, 0, 0, 0, 0, 0, 0};
        if (ok1) a1 = *(const short8*)(ar1 + ks * 32);
        #pragma unroll
        for (int ct = 0; ct < NCT; ++ct) {
            short8 b = wl[(ks * NCT + ct) * 64 + lane];
            acc0[ct] = __builtin_amdgcn_mfma_f32_16x16x32_bf16(a0, b, acc0[ct], 0, 0, 0);
            acc1[ct] = __builtin_amdgcn_mfma_f32_16x16x32_bf16(a1, b, acc1[ct], 0, 0, 0);
        }
    }

    const int r_hi = lane >> 4, col0 = lane & 15;
    #pragma unroll
    for (int ct = 0; ct < NCT; ++ct) {
        float bv = bias[ct * 16 + col0];
        #pragma unroll
        for (int j = 0; j < 4; ++j) {
            float v0 = acc0[ct][j] + bv;
            if (RELU) v0 = fmaxf(v0, 0.f);
            size_t off0 = (size_t)(row0 + r_hi * 4 + j) * ldc + ct * 16 + col0;
            if (BF16OUT) ((unsigned short*)Cout)[off0] = f2bf(v0);
            else         ((float*)Cout)[off0] = v0;
            if (ok1) {
                float v1 = acc1[ct][j] + bv;
                if (RELU) v1 = fmaxf(v1, 0.f);
                size_t off1 = off0 + (size_t)16 * ldc;
                if (BF16OUT) ((unsigned short*)Cout)[off1] = f2bf(v1);
                else         ((float*)Cout)[off1] = v1;
            }
        }
    }
}

// ---------------------------------------------------------------------------
extern "C" void kernel_launch(void* const* d_in, const int* in_sizes, int n_in,
                              void* d_out, int out_size, void* d_ws, size_t ws_size,
                              hipStream_t stream) {
    const float* feat   = (const float*)d_in[0];
    const int*   src    = (const int*)d_in[1];
    const int*   dst    = (const int*)d_in[2];
    const float* Wself1 = (const float*)d_in[3];
    const float* Wneigh1= (const float*)d_in[4];
    const float* b1     = (const float*)d_in[5];
    const float* Wself2 = (const float*)d_in[6];
    const float* Wneigh2= (const float*)d_in[7];
    const float* b2     = (const float*)d_in[8];
    const float* Wout   = (const float*)d_in[9];
    const float* bout   = (const float*)d_in[10];
    float* out = (float*)d_out;
    (void)ws_size;

    // workspace layout
    int* hist    = (int*)d_ws;                          // 25000
    int* segbase = hist + NCTR;                         // 25001 (pad to 25004)
    int* cursor  = segbase + (NCTR + 4);                // 25000
    unsigned int* pack = (unsigned int*)(cursor + NCTR);         // 1.6M
    unsigned short* xcat1 = (unsigned short*)(pack + N_EDGES);   // 100000*256
    unsigned short* xcat2 = xcat1 + (size_t)N_NODES * 256;       // 100000*256
    unsigned short* wp1   = xcat2 + (size_t)N_NODES * 256;       // 256*128
    unsigned short* wp2   = wp1 + 256 * 128;
    unsigned short* wpo   = wp2 + 256 * 128;                     // 128*64
    unsigned short* h2    = xcat1;                               // alias (dead xcat1)

    const int quad_blocks = (N_EDGES / 4 + 255) / 256;  // 1563
    const int cvt_blocks  = (N_NODES * (D / 4) + 255) / 256;
    const int gemm_blocks = (N_NODES + 127) / 128;      // 782

    // ---- edge binning ----
    hipMemsetAsync(hist, 0, NCTR * sizeof(int), stream);
    hist_k<<<quad_blocks, 256, 0, stream>>>(dst, hist);
    scan_k<<<1, 1024, 0, stream>>>(hist, segbase, cursor);
    bin_k<<<quad_blocks, 256, 0, stream>>>(src, dst, cursor, pack);

    // ---- conversions / packing ----
    cvt_feat_k<<<cvt_blocks, 256, 0, stream>>>(feat, xcat1);
    packW_k<256, 128><<<64, 64, 0, stream>>>(Wself1, Wneigh1, wp1);
    packW_k<256, 128><<<64, 64, 0, stream>>>(Wself2, Wneigh2, wp2);
    packW_k<128, 64><<<16, 64, 0, stream>>>(Wout, nullptr, wpo);

    // ---- layer 1 ----
    gather_k<<<NPART, 256, 0, stream>>>(xcat1, pack, segbase, xcat1);
    gemm_k<256, 128, true, true><<<gemm_blocks, 256, 0, stream>>>(
        xcat1, 256, (const short8*)wp1, b1, xcat2, 256);

    // ---- layer 2 ----
    gather_k<<<NPART, 256, 0, stream>>>(xcat2, pack, segbase, xcat2);
    gemm_k<256, 128, true, true><<<gemm_blocks, 256, 0, stream>>>(
        xcat2, 256, (const short8*)wp2, b2, h2, 128);

    // ---- output projection ----
    gemm_k<128, 64, false, false><<<gemm_blocks, 256, 0, stream>>>(
        h2, 128, (const short8*)wpo, bout, out, 64);
}

// Round 7
// 434.146 us; speedup vs baseline: 1.1006x; 1.1006x over previous
//
#include <hip/hip_runtime.h>
#include <hip/hip_bf16.h>

constexpr int N_NODES = 100000;
constexpr int N_EDGES = 1600000;
constexpr int D = 128;
constexpr int N_CLASSES = 64;

constexpr int PART_NODES = 32;                 // nodes per partition
constexpr int NPART = N_NODES / PART_NODES;    // 3125 (exact)
constexpr int NCTR = NPART * 8;                // 25000 (8 shards)
constexpr int CAP = 1024;                      // per-partition edge capacity
                                               // (mean 512, std ~23 -> 1024 is ~22 sigma)

typedef __attribute__((ext_vector_type(8))) short short8;
typedef __attribute__((ext_vector_type(4))) float f32x4;

static __device__ __forceinline__ float bf2f(unsigned int lo16) {
    unsigned int x = lo16 << 16;
    return __builtin_bit_cast(float, x);
}
static __device__ __forceinline__ unsigned short f2bf(float f) {
    unsigned int x = __builtin_bit_cast(unsigned int, f);
    x += 0x7fffu + ((x >> 16) & 1u);          // RNE
    return (unsigned short)(x >> 16);
}

// ---------------------------------------------------------------------------
// 1) histogram edges into (partition, shard) buckets.
//    1024 edges per block, shard = blockIdx&7 (block-constant -> appends to a
//    bucket come from one XCD's L2 in bin_k; hist MUST use the same mapping).
// ---------------------------------------------------------------------------
__global__ __launch_bounds__(256) void hist_k(const int* __restrict__ dst,
                                              int* __restrict__ hist) {
    int e0 = blockIdx.x * 1024 + threadIdx.x * 4;
    if (e0 >= N_EDGES) return;
    int sh = blockIdx.x & 7;
    int4 d = *(const int4*)(dst + e0);
    atomicAdd(hist + (((d.x >> 5) << 3) | sh), 1);
    atomicAdd(hist + (((d.y >> 5) << 3) | sh), 1);
    atomicAdd(hist + (((d.z >> 5) << 3) | sh), 1);
    atomicAdd(hist + (((d.w >> 5) << 3) | sh), 1);
}

// ---------------------------------------------------------------------------
// 2) exclusive scan of the 25000 bucket counts (single block)
// ---------------------------------------------------------------------------
__global__ __launch_bounds__(1024) void scan_k(const int* __restrict__ hist,
                                               int* __restrict__ segbase,
                                               int* __restrict__ cursor) {
    __shared__ int part[1024];
    const int t = threadIdx.x;
    const int CH = (NCTR + 1023) / 1024;       // 25
    int s = 0;
    for (int i = 0; i < CH; ++i) {
        int idx = t * CH + i;
        if (idx < NCTR) s += hist[idx];
    }
    part[t] = s;
    __syncthreads();
    for (int off = 1; off < 1024; off <<= 1) {
        int v = (t >= off) ? part[t - off] : 0;
        __syncthreads();
        part[t] += v;
        __syncthreads();
    }
    int base = (t == 0) ? 0 : part[t - 1];
    for (int i = 0; i < CH; ++i) {
        int idx = t * CH + i;
        if (idx < NCTR) {
            segbase[idx] = base;
            cursor[idx]  = base;
            base += hist[idx];
        }
    }
    if (t == 1023) segbase[NCTR] = base;       // == N_EDGES
}

// ---------------------------------------------------------------------------
// 3) bin: append packed (dst_local<<17 | src) — same shard mapping as hist_k
// ---------------------------------------------------------------------------
__global__ __launch_bounds__(256) void bin_k(const int* __restrict__ src,
                                             const int* __restrict__ dst,
                                             int* __restrict__ cursor,
                                             unsigned int* __restrict__ pack) {
    int e0 = blockIdx.x * 1024 + threadIdx.x * 4;
    if (e0 >= N_EDGES) return;
    int sh = blockIdx.x & 7;
    int4 d = *(const int4*)(dst + e0);
    int4 s = *(const int4*)(src + e0);
    int p0 = atomicAdd(cursor + (((d.x >> 5) << 3) | sh), 1);
    int p1 = atomicAdd(cursor + (((d.y >> 5) << 3) | sh), 1);
    int p2 = atomicAdd(cursor + (((d.z >> 5) << 3) | sh), 1);
    int p3 = atomicAdd(cursor + (((d.w >> 5) << 3) | sh), 1);
    pack[p0] = ((unsigned int)(d.x & 31) << 17) | (unsigned int)s.x;
    pack[p1] = ((unsigned int)(d.y & 31) << 17) | (unsigned int)s.y;
    pack[p2] = ((unsigned int)(d.z & 31) << 17) | (unsigned int)s.z;
    pack[p3] = ((unsigned int)(d.w & 31) << 17) | (unsigned int)s.w;
}

// ---------------------------------------------------------------------------
// feat fp32 -> bf16, flat copy into fbuf[N][128]
// ---------------------------------------------------------------------------
__global__ __launch_bounds__(256) void cvt_feat_k(const float* __restrict__ feat,
                                                  unsigned short* __restrict__ fbuf) {
    int i = blockIdx.x * 256 + threadIdx.x;    // float4 chunks, 3.2M total
    if (i >= N_NODES * (D / 4)) return;
    float4 v = ((const float4*)feat)[i];
    ushort4 r;
    r.x = f2bf(v.x); r.y = f2bf(v.y); r.z = f2bf(v.z); r.w = f2bf(v.w);
    ((ushort4*)fbuf)[i] = r;
}

// ---------------------------------------------------------------------------
// pack all 3 weight matrices into MFMA B-fragment order (one launch):
// wp[((kstep*NCT+ct)*64+lane)*8+j] = W[kstep*32+(lane>>4)*8+j][ct*16+(lane&15)]
// blocks 0..63: wp1, 64..127: wp2, 128..143: wpo
// ---------------------------------------------------------------------------
__global__ __launch_bounds__(64) void packAll_k(const float* __restrict__ Ws1,
                                                const float* __restrict__ Wn1,
                                                const float* __restrict__ Ws2,
                                                const float* __restrict__ Wn2,
                                                const float* __restrict__ Wo,
                                                unsigned short* __restrict__ wp1,
                                                unsigned short* __restrict__ wp2,
                                                unsigned short* __restrict__ wpo) {
    int b = blockIdx.x;
    const float *Wa, *Wb;
    unsigned short* wp;
    int DOUT, bb;
    if (b < 64)       { Wa = Ws1; Wb = Wn1; wp = wp1; DOUT = 128; bb = b; }
    else if (b < 128) { Wa = Ws2; Wb = Wn2; wp = wp2; DOUT = 128; bb = b - 64; }
    else              { Wa = Wo;  Wb = nullptr; wp = wpo; DOUT = 64; bb = b - 128; }
    int NCT = DOUT / 16;
    int kstep = bb / NCT;
    int ct = bb % NCT;
    int lane = threadIdx.x;
    int col = ct * 16 + (lane & 15);
    int kbase = kstep * 32 + (lane >> 4) * 8;
    unsigned short r[8];
    #pragma unroll
    for (int j = 0; j < 8; ++j) {
        int k = kbase + j;
        float w = (k < 128) ? Wa[(size_t)k * DOUT + col]
                            : Wb[(size_t)(k - 128) * DOUT + col];
        r[j] = f2bf(w);
    }
    *(short8*)(wp + ((size_t)((kstep * NCT + ct) * 64 + lane)) * 8) =
        *(const short8*)r;
}

// ---------------------------------------------------------------------------
// 4) FUSED layer: one block per partition (32 nodes).
//    Phase A: stage bucket edges in LDS + 32-bin counting sort, then register
//             gather (16 lanes x dwordx4 cover a 256 B row, 4 edges/wave-load),
//             shfl-fold, write mean to padded LDS tile [32][136] bf16.
//    Phase B: MFMA GEMM out = relu([self | mean] @ W + b), self from global,
//             mean from LDS, W fragments from L2-hot packed buffer.
// ---------------------------------------------------------------------------
__global__ __launch_bounds__(256) void fused_k(const unsigned short* __restrict__ xin,
                                               const unsigned int* __restrict__ pack,
                                               const int* __restrict__ segbase,
                                               const short8* __restrict__ wp,
                                               const float* __restrict__ bias,
                                               unsigned short* __restrict__ xout) {
    __shared__ unsigned int eraw[CAP];
    __shared__ unsigned int ssrc[CAP];
    __shared__ int bcnt[32];
    __shared__ int boff[33];
    __shared__ unsigned short mlds[PART_NODES][136];   // stride 272 B: 2-way banks

    const int t = threadIdx.x;
    const int p = blockIdx.x;
    const int beg = segbase[p << 3];
    const int end = segbase[(p + 1) << 3];
    const int n = (end - beg) < CAP ? (end - beg) : CAP;

    if (t < 32) bcnt[t] = 0;
    __syncthreads();

    for (int i = t; i < n; i += 256) {
        unsigned int pk = pack[beg + i];
        eraw[i] = pk;
        atomicAdd(&bcnt[pk >> 17], 1);
    }
    __syncthreads();

    if (t == 0) {
        int s = 0;
        #pragma unroll
        for (int i = 0; i < 32; ++i) { boff[i] = s; s += bcnt[i]; }
        boff[32] = s;
    }
    __syncthreads();
    if (t < 32) bcnt[t] = boff[t];             // reuse as cursor
    __syncthreads();

    for (int i = t; i < n; i += 256) {
        unsigned int pk = eraw[i];
        int pos = atomicAdd(&bcnt[pk >> 17], 1);
        ssrc[pos] = pk & 0x1ffffu;
    }
    __syncthreads();

    // ---- phase A: gather into mlds ----
    const int w = t >> 6, lane = t & 63;
    const int sub = lane >> 4;                 // edge slot 0..3
    const int cl = lane & 15;                  // column group (cols cl*8..+7)

    for (int g = 0; g < 8; ++g) {
        const int ni = w * 8 + g;
        const int b = boff[ni];
        const int eN = boff[ni + 1];

        float acc[8];
        #pragma unroll
        for (int r = 0; r < 8; ++r) acc[r] = 0.f;

        for (int i = b + sub; i < eN; i += 4) {
            int s = ssrc[i];
            uint4 u = *(const uint4*)(xin + (size_t)s * 128 + cl * 8);
            acc[0] += bf2f(u.x & 0xffffu); acc[1] += bf2f(u.x >> 16);
            acc[2] += bf2f(u.y & 0xffffu); acc[3] += bf2f(u.y >> 16);
            acc[4] += bf2f(u.z & 0xffffu); acc[5] += bf2f(u.z >> 16);
            acc[6] += bf2f(u.w & 0xffffu); acc[7] += bf2f(u.w >> 16);
        }
        #pragma unroll
        for (int r = 0; r < 8; ++r) {
            acc[r] += __shfl_xor(acc[r], 16);
            acc[r] += __shfl_xor(acc[r], 32);
        }
        float inv = 1.0f / fmaxf((float)(eN - b), 1.0f);
        float lo = acc[sub * 2 + 0] * inv;
        float hi = acc[sub * 2 + 1] * inv;
        unsigned int o = ((unsigned int)f2bf(hi) << 16) | (unsigned int)f2bf(lo);
        *(unsigned int*)(&mlds[ni][cl * 8 + sub * 2]) = o;
    }
    __syncthreads();

    // ---- phase B: 32-row GEMM, K=256 (self 0..127 global, mean 128..255 LDS) ----
    const int frag = w & 1;                    // 16-row fragment 0/1
    const int cg0 = (w >> 1) * 4;              // col-tile group base (of 8)
    const int r15 = lane & 15;
    const int khi = lane >> 4;                 // 0..3
    const int row0 = p * PART_NODES + frag * 16;
    const unsigned short* arow = xin + (size_t)(row0 + r15) * 128 + khi * 8;

    f32x4 acc[4];
    #pragma unroll
    for (int c = 0; c < 4; ++c) acc[c] = {0.f, 0.f, 0.f, 0.f};

    #pragma unroll
    for (int ks = 0; ks < 8; ++ks) {
        short8 a;
        if (ks < 4) a = *(const short8*)(arow + ks * 32);
        else        a = *(const short8*)(&mlds[frag * 16 + r15][(ks - 4) * 32 + khi * 8]);
        #pragma unroll
        for (int c = 0; c < 4; ++c) {
            short8 b = wp[(ks * 8 + cg0 + c) * 64 + lane];
            acc[c] = __builtin_amdgcn_mfma_f32_16x16x32_bf16(a, b, acc[c], 0, 0, 0);
        }
    }

    const int rhi = lane >> 4, col0 = lane & 15;
    #pragma unroll
    for (int c = 0; c < 4; ++c) {
        float bv = bias[(cg0 + c) * 16 + col0];
        #pragma unroll
        for (int j = 0; j < 4; ++j) {
            float v = fmaxf(acc[c][j] + bv, 0.f);
            xout[(size_t)(row0 + rhi * 4 + j) * 128 + (cg0 + c) * 16 + col0] = f2bf(v);
        }
    }
}

// ---------------------------------------------------------------------------
// output GEMM: C[M x 64] = A[M x 128] @ W + b (fp32 out, no relu).
// W staged in LDS; 4 waves, 32 rows/wave.
// ---------------------------------------------------------------------------
__global__ __launch_bounds__(256) void outgemm_k(const unsigned short* __restrict__ A,
                                                 const short8* __restrict__ Wp,
                                                 const float* __restrict__ bias,
                                                 float* __restrict__ Cout) {
    constexpr int NCT = N_CLASSES / 16;        // 4
    constexpr int KST = D / 32;                // 4
    constexpr int NW8 = KST * NCT * 64;        // 1024 (16 KB)
    __shared__ short8 wl[NW8];
    const int t = threadIdx.x;
    #pragma unroll
    for (int i = 0; i < NW8 / 256; ++i) wl[t + i * 256] = Wp[t + i * 256];
    __syncthreads();

    const int wid = t >> 6, lane = t & 63;
    const int row0 = blockIdx.x * 128 + wid * 32;
    if (row0 + 16 > N_NODES) return;
    const bool ok1 = (row0 + 32 <= N_NODES);

    const unsigned short* ar0 = A + (size_t)(row0 + (lane & 15)) * D + (lane >> 4) * 8;
    const unsigned short* ar1 = ar0 + (size_t)16 * D;

    f32x4 acc0[NCT], acc1[NCT];
    #pragma unroll
    for (int ct = 0; ct < NCT; ++ct) {
        acc0[ct] = {0.f, 0.f, 0.f, 0.f};
        acc1[ct] = {0.f, 0.f, 0.f, 0.f};
    }

    #pragma unroll
    for (int ks = 0; ks < KST; ++ks) {
        short8 a0 = *(const short8*)(ar0 + ks * 32);
        short8 a1 = {0, 0, 0, 0, 0, 0, 0, 0};
        if (ok1) a1 = *(const short8*)(ar1 + ks * 32);
        #pragma unroll
        for (int ct = 0; ct < NCT; ++ct) {
            short8 b = wl[(ks * NCT + ct) * 64 + lane];
            acc0[ct] = __builtin_amdgcn_mfma_f32_16x16x32_bf16(a0, b, acc0[ct], 0, 0, 0);
            acc1[ct] = __builtin_amdgcn_mfma_f32_16x16x32_bf16(a1, b, acc1[ct], 0, 0, 0);
        }
    }

    const int r_hi = lane >> 4, col0 = lane & 15;
    #pragma unroll
    for (int ct = 0; ct < NCT; ++ct) {
        float bv = bias[ct * 16 + col0];
        #pragma unroll
        for (int j = 0; j < 4; ++j) {
            size_t off0 = (size_t)(row0 + r_hi * 4 + j) * N_CLASSES + ct * 16 + col0;
            Cout[off0] = acc0[ct][j] + bv;
            if (ok1) Cout[off0 + (size_t)16 * N_CLASSES] = acc1[ct][j] + bv;
        }
    }
}

// ---------------------------------------------------------------------------
extern "C" void kernel_launch(void* const* d_in, const int* in_sizes, int n_in,
                              void* d_out, int out_size, void* d_ws, size_t ws_size,
                              hipStream_t stream) {
    const float* feat   = (const float*)d_in[0];
    const int*   src    = (const int*)d_in[1];
    const int*   dst    = (const int*)d_in[2];
    const float* Wself1 = (const float*)d_in[3];
    const float* Wneigh1= (const float*)d_in[4];
    const float* b1     = (const float*)d_in[5];
    const float* Wself2 = (const float*)d_in[6];
    const float* Wneigh2= (const float*)d_in[7];
    const float* b2     = (const float*)d_in[8];
    const float* Wout   = (const float*)d_in[9];
    const float* bout   = (const float*)d_in[10];
    float* out = (float*)d_out;
    (void)ws_size;

    // workspace layout
    int* hist    = (int*)d_ws;                          // 25000
    int* segbase = hist + NCTR;                         // 25001 (pad to 25004)
    int* cursor  = segbase + (NCTR + 4);                // 25000
    unsigned int* pack = (unsigned int*)(cursor + NCTR);          // 1.6M
    unsigned short* fbuf1 = (unsigned short*)(pack + N_EDGES);    // N*128 bf16
    unsigned short* h1    = fbuf1 + (size_t)N_NODES * D;          // N*128 bf16
    unsigned short* wp1   = h1 + (size_t)N_NODES * D;             // 256*128
    unsigned short* wp2   = wp1 + 256 * 128;
    unsigned short* wpo   = wp2 + 256 * 128;                      // 128*64
    unsigned short* h2    = fbuf1;                                // alias (dead)

    const int ebin_blocks = (N_EDGES + 1023) / 1024;    // 1563
    const int cvt_blocks  = (N_NODES * (D / 4) + 255) / 256;
    const int ogemm_blocks = (N_NODES + 127) / 128;     // 782

    // ---- edge binning ----
    hipMemsetAsync(hist, 0, NCTR * sizeof(int), stream);
    hist_k<<<ebin_blocks, 256, 0, stream>>>(dst, hist);
    scan_k<<<1, 1024, 0, stream>>>(hist, segbase, cursor);
    bin_k<<<ebin_blocks, 256, 0, stream>>>(src, dst, cursor, pack);

    // ---- conversions / packing ----
    cvt_feat_k<<<cvt_blocks, 256, 0, stream>>>(feat, fbuf1);
    packAll_k<<<144, 64, 0, stream>>>(Wself1, Wneigh1, Wself2, Wneigh2, Wout,
                                      wp1, wp2, wpo);

    // ---- layer 1 (fused gather+GEMM) ----
    fused_k<<<NPART, 256, 0, stream>>>(fbuf1, pack, segbase,
                                       (const short8*)wp1, b1, h1);

    // ---- layer 2 (fused gather+GEMM) ----
    fused_k<<<NPART, 256, 0, stream>>>(h1, pack, segbase,
                                       (const short8*)wp2, b2, h2);

    // ---- output projection ----
    outgemm_k<<<ogemm_blocks, 256, 0, stream>>>(h2, (const short8*)wpo, bout, out);
}

// Round 8
// 377.505 us; speedup vs baseline: 1.2657x; 1.1500x over previous
//
#include <hip/hip_runtime.h>
#include <hip/hip_bf16.h>

constexpr int N_NODES = 100000;
constexpr int N_EDGES = 1600000;
constexpr int D = 128;
constexpr int N_CLASSES = 64;

constexpr int PART_NODES = 32;                 // nodes per partition
constexpr int NPART = N_NODES / PART_NODES;    // 3125 (exact)
constexpr int NCTR = NPART * 8;                // 25000 (8 shards)
constexpr int CAP = 1024;                      // per-partition edge capacity
constexpr int EB = (N_EDGES + 1023) / 1024;    // 1563 hist/bin blocks
constexpr int CVTB = N_NODES * (D / 4) / 256;  // 12500 cvt blocks (exact)
constexpr int SCH = (NCTR + 1023) / 1024;      // 25 per-thread scan chunk

typedef __attribute__((ext_vector_type(8))) short short8;
typedef __attribute__((ext_vector_type(4))) float f32x4;

static __device__ __forceinline__ float bf2f(unsigned int lo16) {
    unsigned int x = lo16 << 16;
    return __builtin_bit_cast(float, x);
}
static __device__ __forceinline__ unsigned short f2bf(float f) {
    unsigned int x = __builtin_bit_cast(unsigned int, f);
    x += 0x7fffu + ((x >> 16) & 1u);          // RNE
    return (unsigned short)(x >> 16);
}

// ---------------------------------------------------------------------------
// 1) hist (blocks 0..EB-1, shard = blockIdx&7, MUST match bin_k)  ∥
//    feat fp32 -> bf16 (blocks EB..EB+CVTB-1)
// ---------------------------------------------------------------------------
__global__ __launch_bounds__(256) void histcvt_k(const int* __restrict__ dst,
                                                 int* __restrict__ hist,
                                                 const float* __restrict__ feat,
                                                 unsigned short* __restrict__ fbuf) {
    const int b = blockIdx.x;
    const int t = threadIdx.x;
    if (b < EB) {
        int e0 = b * 1024 + t * 4;
        if (e0 >= N_EDGES) return;
        int sh = b & 7;
        int4 d = *(const int4*)(dst + e0);
        atomicAdd(hist + (((d.x >> 5) << 3) | sh), 1);
        atomicAdd(hist + (((d.y >> 5) << 3) | sh), 1);
        atomicAdd(hist + (((d.z >> 5) << 3) | sh), 1);
        atomicAdd(hist + (((d.w >> 5) << 3) | sh), 1);
    } else {
        int i = (b - EB) * 256 + t;            // float4 chunk id, 3.2M exact
        float4 v = ((const float4*)feat)[i];
        ushort4 r;
        r.x = f2bf(v.x); r.y = f2bf(v.y); r.z = f2bf(v.z); r.w = f2bf(v.w);
        ((ushort4*)fbuf)[i] = r;
    }
}

// ---------------------------------------------------------------------------
// 2) block 0: exclusive scan of 25000 counts, fully in LDS (coalesced global
//    IO)  ∥  blocks 1..9: pack the 3 weight matrices into MFMA B-frag order
// ---------------------------------------------------------------------------
__global__ __launch_bounds__(1024) void scanpack_k(const int* __restrict__ hist,
                                                   int* __restrict__ segbase,
                                                   int* __restrict__ cursor,
                                                   const float* __restrict__ Ws1,
                                                   const float* __restrict__ Wn1,
                                                   const float* __restrict__ Ws2,
                                                   const float* __restrict__ Wn2,
                                                   const float* __restrict__ Wo,
                                                   unsigned short* __restrict__ wp1,
                                                   unsigned short* __restrict__ wp2,
                                                   unsigned short* __restrict__ wpo) {
    const int t = threadIdx.x;
    if (blockIdx.x == 0) {
        __shared__ int lds[NCTR];              // 100 KB
        __shared__ int psum[1024];
        for (int i = t; i < NCTR; i += 1024) lds[i] = hist[i];   // coalesced
        __syncthreads();
        const int c0 = t * SCH;
        const int c1 = (c0 + SCH < NCTR) ? c0 + SCH : NCTR;
        int s = 0;
        for (int i = c0; i < c1; ++i) s += lds[i];
        psum[t] = s;
        __syncthreads();
        for (int off = 1; off < 1024; off <<= 1) {
            int v = (t >= off) ? psum[t - off] : 0;
            __syncthreads();
            psum[t] += v;
            __syncthreads();
        }
        int base = (t == 0) ? 0 : psum[t - 1];
        for (int i = c0; i < c1; ++i) { int v = lds[i]; lds[i] = base; base += v; }
        __syncthreads();
        for (int i = t; i < NCTR; i += 1024) {                   // coalesced
            int v = lds[i];
            segbase[i] = v;
            cursor[i] = v;
        }
        if (t == 0) segbase[NCTR] = N_EDGES;
    } else {
        int g = (blockIdx.x - 1) * 16 + (t >> 6);                // tile 0..143
        if (g >= 144) return;
        int lane = t & 63;
        const float *Wa, *Wb;
        unsigned short* wp;
        int DOUT, bb;
        if (g < 64)       { Wa = Ws1; Wb = Wn1; wp = wp1; DOUT = 128; bb = g; }
        else if (g < 128) { Wa = Ws2; Wb = Wn2; wp = wp2; DOUT = 128; bb = g - 64; }
        else              { Wa = Wo;  Wb = nullptr; wp = wpo; DOUT = 64; bb = g - 128; }
        int NCT = DOUT / 16;
        int kstep = bb / NCT;
        int ct = bb % NCT;
        int col = ct * 16 + (lane & 15);
        int kbase = kstep * 32 + (lane >> 4) * 8;
        unsigned short r[8];
        #pragma unroll
        for (int j = 0; j < 8; ++j) {
            int k = kbase + j;
            float w = (k < 128) ? Wa[(size_t)k * DOUT + col]
                                : Wb[(size_t)(k - 128) * DOUT + col];
            r[j] = f2bf(w);
        }
        *(short8*)(wp + ((size_t)((kstep * NCT + ct) * 64 + lane)) * 8) =
            *(const short8*)r;
    }
}

// ---------------------------------------------------------------------------
// 3) bin: append packed (dst_local<<17 | src) — same shard mapping as hist
// ---------------------------------------------------------------------------
__global__ __launch_bounds__(256) void bin_k(const int* __restrict__ src,
                                             const int* __restrict__ dst,
                                             int* __restrict__ cursor,
                                             unsigned int* __restrict__ pack) {
    int e0 = blockIdx.x * 1024 + threadIdx.x * 4;
    if (e0 >= N_EDGES) return;
    int sh = blockIdx.x & 7;
    int4 d = *(const int4*)(dst + e0);
    int4 s = *(const int4*)(src + e0);
    int p0 = atomicAdd(cursor + (((d.x >> 5) << 3) | sh), 1);
    int p1 = atomicAdd(cursor + (((d.y >> 5) << 3) | sh), 1);
    int p2 = atomicAdd(cursor + (((d.z >> 5) << 3) | sh), 1);
    int p3 = atomicAdd(cursor + (((d.w >> 5) << 3) | sh), 1);
    pack[p0] = ((unsigned int)(d.x & 31) << 17) | (unsigned int)s.x;
    pack[p1] = ((unsigned int)(d.y & 31) << 17) | (unsigned int)s.y;
    pack[p2] = ((unsigned int)(d.z & 31) << 17) | (unsigned int)s.z;
    pack[p3] = ((unsigned int)(d.w & 31) << 17) | (unsigned int)s.w;
}

// ---------------------------------------------------------------------------
// 4) FUSED layer: one block per partition (32 nodes).
//    Phase A: LDS counting sort + register gather -> mean in LDS tile.
//    Phase B: MFMA GEMM h = relu([self | mean] @ W + b).
//    OUTPROJ: restage h tile in LDS, phase C MFMA out = h @ Wout + bout (fp32).
// ---------------------------------------------------------------------------
template <bool OUTPROJ>
__global__ __launch_bounds__(256) void fused_k(const unsigned short* __restrict__ xin,
                                               const unsigned int* __restrict__ pack,
                                               const int* __restrict__ segbase,
                                               const short8* __restrict__ wp,
                                               const float* __restrict__ bias,
                                               unsigned short* __restrict__ xout,
                                               const short8* __restrict__ wpo,
                                               const float* __restrict__ bout,
                                               float* __restrict__ outp) {
    __shared__ unsigned int eraw[CAP];
    __shared__ unsigned int ssrc[CAP];
    __shared__ int bcnt[32];
    __shared__ int boff[33];
    __shared__ unsigned short mlds[PART_NODES][136];   // stride 272 B

    const int t = threadIdx.x;
    const int p = blockIdx.x;
    const int beg = segbase[p << 3];
    const int end = segbase[(p + 1) << 3];
    const int n = (end - beg) < CAP ? (end - beg) : CAP;

    if (t < 32) bcnt[t] = 0;
    __syncthreads();

    for (int i = t; i < n; i += 256) {
        unsigned int pk = pack[beg + i];
        eraw[i] = pk;
        atomicAdd(&bcnt[pk >> 17], 1);
    }
    __syncthreads();

    if (t == 0) {
        int s = 0;
        #pragma unroll
        for (int i = 0; i < 32; ++i) { boff[i] = s; s += bcnt[i]; }
        boff[32] = s;
    }
    __syncthreads();
    if (t < 32) bcnt[t] = boff[t];             // reuse as cursor
    __syncthreads();

    for (int i = t; i < n; i += 256) {
        unsigned int pk = eraw[i];
        int pos = atomicAdd(&bcnt[pk >> 17], 1);
        ssrc[pos] = pk & 0x1ffffu;
    }
    __syncthreads();

    // ---- phase A: gather into mlds ----
    const int w = t >> 6, lane = t & 63;
    const int sub = lane >> 4;                 // edge slot 0..3
    const int cl = lane & 15;                  // column group (cols cl*8..+7)

    for (int g = 0; g < 8; ++g) {
        const int ni = w * 8 + g;
        const int b = boff[ni];
        const int eN = boff[ni + 1];

        float acc[8];
        #pragma unroll
        for (int r = 0; r < 8; ++r) acc[r] = 0.f;

        for (int i = b + sub; i < eN; i += 4) {
            int s = ssrc[i];
            uint4 u = *(const uint4*)(xin + (size_t)s * 128 + cl * 8);
            acc[0] += bf2f(u.x & 0xffffu); acc[1] += bf2f(u.x >> 16);
            acc[2] += bf2f(u.y & 0xffffu); acc[3] += bf2f(u.y >> 16);
            acc[4] += bf2f(u.z & 0xffffu); acc[5] += bf2f(u.z >> 16);
            acc[6] += bf2f(u.w & 0xffffu); acc[7] += bf2f(u.w >> 16);
        }
        #pragma unroll
        for (int r = 0; r < 8; ++r) {
            acc[r] += __shfl_xor(acc[r], 16);
            acc[r] += __shfl_xor(acc[r], 32);
        }
        float inv = 1.0f / fmaxf((float)(eN - b), 1.0f);
        float lo = acc[sub * 2 + 0] * inv;
        float hi = acc[sub * 2 + 1] * inv;
        unsigned int o = ((unsigned int)f2bf(hi) << 16) | (unsigned int)f2bf(lo);
        *(unsigned int*)(&mlds[ni][cl * 8 + sub * 2]) = o;
    }
    __syncthreads();

    // ---- phase B: 32-row GEMM, K=256 (self 0..127 global, mean 128..255 LDS) ----
    const int frag = w & 1;                    // 16-row fragment 0/1
    const int cg0 = (w >> 1) * 4;              // col-tile group base (of 8)
    const int r15 = lane & 15;
    const int khi = lane >> 4;                 // 0..3
    const int row0 = p * PART_NODES + frag * 16;
    const unsigned short* arow = xin + (size_t)(row0 + r15) * 128 + khi * 8;

    f32x4 acc[4];
    #pragma unroll
    for (int c = 0; c < 4; ++c) acc[c] = {0.f, 0.f, 0.f, 0.f};

    #pragma unroll
    for (int ks = 0; ks < 8; ++ks) {
        short8 a;
        if (ks < 4) a = *(const short8*)(arow + ks * 32);
        else        a = *(const short8*)(&mlds[frag * 16 + r15][(ks - 4) * 32 + khi * 8]);
        #pragma unroll
        for (int c = 0; c < 4; ++c) {
            short8 b = wp[(ks * 8 + cg0 + c) * 64 + lane];
            acc[c] = __builtin_amdgcn_mfma_f32_16x16x32_bf16(a, b, acc[c], 0, 0, 0);
        }
    }

    const int rhi = khi, col0 = r15;
    if (!OUTPROJ) {
        #pragma unroll
        for (int c = 0; c < 4; ++c) {
            float bv = bias[(cg0 + c) * 16 + col0];
            #pragma unroll
            for (int j = 0; j < 4; ++j) {
                float v = fmaxf(acc[c][j] + bv, 0.f);
                xout[(size_t)(row0 + rhi * 4 + j) * 128 + (cg0 + c) * 16 + col0] = f2bf(v);
            }
        }
    } else {
        __syncthreads();                        // all mlds reads done
        // restage h tile (bias+relu) into mlds as bf16
        #pragma unroll
        for (int c = 0; c < 4; ++c) {
            float bv = bias[(cg0 + c) * 16 + col0];
            #pragma unroll
            for (int j = 0; j < 4; ++j) {
                float v = fmaxf(acc[c][j] + bv, 0.f);
                mlds[frag * 16 + rhi * 4 + j][(cg0 + c) * 16 + col0] = f2bf(v);
            }
        }
        __syncthreads();
        // ---- phase C: out[32 x 64] = h[32 x 128] @ Wout + bout ----
        const int frag2 = w & 1;
        const int ct0 = (w >> 1) * 2;          // 2 col-tiles of 4
        f32x4 oacc[2];
        oacc[0] = {0.f, 0.f, 0.f, 0.f};
        oacc[1] = {0.f, 0.f, 0.f, 0.f};
        #pragma unroll
        for (int ks = 0; ks < 4; ++ks) {
            short8 a = *(const short8*)(&mlds[frag2 * 16 + r15][ks * 32 + khi * 8]);
            #pragma unroll
            for (int c = 0; c < 2; ++c) {
                short8 b = wpo[(ks * 4 + ct0 + c) * 64 + lane];
                oacc[c] = __builtin_amdgcn_mfma_f32_16x16x32_bf16(a, b, oacc[c], 0, 0, 0);
            }
        }
        #pragma unroll
        for (int c = 0; c < 2; ++c) {
            float bv = bout[(ct0 + c) * 16 + col0];
            #pragma unroll
            for (int j = 0; j < 4; ++j) {
                outp[(size_t)(p * PART_NODES + frag2 * 16 + rhi * 4 + j) * N_CLASSES
                     + (ct0 + c) * 16 + col0] = oacc[c][j] + bv;
            }
        }
    }
}

// ---------------------------------------------------------------------------
extern "C" void kernel_launch(void* const* d_in, const int* in_sizes, int n_in,
                              void* d_out, int out_size, void* d_ws, size_t ws_size,
                              hipStream_t stream) {
    const float* feat   = (const float*)d_in[0];
    const int*   src    = (const int*)d_in[1];
    const int*   dst    = (const int*)d_in[2];
    const float* Wself1 = (const float*)d_in[3];
    const float* Wneigh1= (const float*)d_in[4];
    const float* b1     = (const float*)d_in[5];
    const float* Wself2 = (const float*)d_in[6];
    const float* Wneigh2= (const float*)d_in[7];
    const float* b2     = (const float*)d_in[8];
    const float* Wout   = (const float*)d_in[9];
    const float* bout   = (const float*)d_in[10];
    float* out = (float*)d_out;
    (void)ws_size;

    // workspace layout
    int* hist    = (int*)d_ws;                          // 25000
    int* segbase = hist + NCTR;                         // 25001 (pad to 25004)
    int* cursor  = segbase + (NCTR + 4);                // 25000
    unsigned int* pack = (unsigned int*)(cursor + NCTR);          // 1.6M
    unsigned short* fbuf1 = (unsigned short*)(pack + N_EDGES);    // N*128 bf16
    unsigned short* h1    = fbuf1 + (size_t)N_NODES * D;          // N*128 bf16
    unsigned short* wp1   = h1 + (size_t)N_NODES * D;             // 256*128
    unsigned short* wp2   = wp1 + 256 * 128;
    unsigned short* wpo   = wp2 + 256 * 128;                      // 128*64

    // ---- hist ∥ cvt ----
    hipMemsetAsync(hist, 0, NCTR * sizeof(int), stream);
    histcvt_k<<<EB + CVTB, 256, 0, stream>>>(dst, hist, feat, fbuf1);

    // ---- scan ∥ weight pack ----
    scanpack_k<<<10, 1024, 0, stream>>>(hist, segbase, cursor,
                                        Wself1, Wneigh1, Wself2, Wneigh2, Wout,
                                        wp1, wp2, wpo);

    // ---- bin ----
    bin_k<<<EB, 256, 0, stream>>>(src, dst, cursor, pack);

    // ---- layer 1 (fused gather+GEMM) ----
    fused_k<false><<<NPART, 256, 0, stream>>>(fbuf1, pack, segbase,
                                              (const short8*)wp1, b1, h1,
                                              nullptr, nullptr, nullptr);

    // ---- layer 2 + output projection (fused gather+GEMM+GEMM) ----
    fused_k<true><<<NPART, 256, 0, stream>>>(h1, pack, segbase,
                                             (const short8*)wp2, b2, nullptr,
                                             (const short8*)wpo, bout, out);
}

// Round 9
// 298.680 us; speedup vs baseline: 1.5997x; 1.2639x over previous
//
#include <hip/hip_runtime.h>
#include <hip/hip_bf16.h>

constexpr int N_NODES = 100000;
constexpr int N_EDGES = 1600000;
constexpr int D = 128;
constexpr int N_CLASSES = 64;

constexpr int PART_NODES = 32;                 // nodes per partition
constexpr int NPART = N_NODES / PART_NODES;    // 3125 (exact)
constexpr int NCTR = NPART * 8;                // 25000 (8 shards)
constexpr int CAP_SH = 128;                    // slab entries per (part,shard)
                                               // mean 64, sigma 8 -> 8 sigma
constexpr int CAPT = 8 * CAP_SH;               // 1024 per partition
constexpr int EB = (N_EDGES + 1023) / 1024;    // 1563 bin blocks
constexpr int CIB = (NCTR + 255) / 256;        // 98 cursor-init blocks
constexpr int CVTB = N_NODES * (D / 4) / 256;  // 12500 cvt blocks (exact)
constexpr int PKB = 36;                        // 144 weight tiles / 4 per block

typedef __attribute__((ext_vector_type(8))) short short8;
typedef __attribute__((ext_vector_type(4))) float f32x4;

static __device__ __forceinline__ float bf2f(unsigned int lo16) {
    unsigned int x = lo16 << 16;
    return __builtin_bit_cast(float, x);
}
static __device__ __forceinline__ unsigned short f2bf(float f) {
    unsigned int x = __builtin_bit_cast(unsigned int, f);
    x += 0x7fffu + ((x >> 16) & 1u);          // RNE
    return (unsigned short)(x >> 16);
}

// ---------------------------------------------------------------------------
// 1) prep: cursor init (slab bases)  ∥  feat fp32->bf16  ∥  weight packing
// ---------------------------------------------------------------------------
__global__ __launch_bounds__(256) void prep_k(int* __restrict__ cursor,
                                              const float* __restrict__ feat,
                                              unsigned short* __restrict__ fbuf,
                                              const float* __restrict__ Ws1,
                                              const float* __restrict__ Wn1,
                                              const float* __restrict__ Ws2,
                                              const float* __restrict__ Wn2,
                                              const float* __restrict__ Wo,
                                              unsigned short* __restrict__ wp1,
                                              unsigned short* __restrict__ wp2,
                                              unsigned short* __restrict__ wpo) {
    const int b = blockIdx.x;
    const int t = threadIdx.x;
    if (b < CIB) {
        int i = b * 256 + t;
        if (i < NCTR) cursor[i] = i << 7;      // i * CAP_SH
    } else if (b < CIB + CVTB) {
        int i = (b - CIB) * 256 + t;           // float4 chunk id, 3.2M exact
        float4 v = ((const float4*)feat)[i];
        ushort4 r;
        r.x = f2bf(v.x); r.y = f2bf(v.y); r.z = f2bf(v.z); r.w = f2bf(v.w);
        ((ushort4*)fbuf)[i] = r;
    } else {
        int g = (b - CIB - CVTB) * 4 + (t >> 6);   // weight tile 0..143
        if (g >= 144) return;
        int lane = t & 63;
        const float *Wa, *Wb;
        unsigned short* wp;
        int DOUT, bb;
        if (g < 64)       { Wa = Ws1; Wb = Wn1; wp = wp1; DOUT = 128; bb = g; }
        else if (g < 128) { Wa = Ws2; Wb = Wn2; wp = wp2; DOUT = 128; bb = g - 64; }
        else              { Wa = Wo;  Wb = nullptr; wp = wpo; DOUT = 64; bb = g - 128; }
        int NCT = DOUT / 16;
        int kstep = bb / NCT;
        int ct = bb % NCT;
        int col = ct * 16 + (lane & 15);
        int kbase = kstep * 32 + (lane >> 4) * 8;
        unsigned short r[8];
        #pragma unroll
        for (int j = 0; j < 8; ++j) {
            int k = kbase + j;
            float w = (k < 128) ? Wa[(size_t)k * DOUT + col]
                                : Wb[(size_t)(k - 128) * DOUT + col];
            r[j] = f2bf(w);
        }
        *(short8*)(wp + ((size_t)((kstep * NCT + ct) * 64 + lane)) * 8) =
            *(const short8*)r;
    }
}

// ---------------------------------------------------------------------------
// 2) bin: append packed (dst_local<<17 | src) into fixed slabs.
//    shard = blockIdx&7 (block-constant -> appends to a slab tail come from
//    ~one XCD's L2). Guarded against (astronomically unlikely) slab overflow.
// ---------------------------------------------------------------------------
__global__ __launch_bounds__(256) void bin_k(const int* __restrict__ src,
                                             const int* __restrict__ dst,
                                             int* __restrict__ cursor,
                                             unsigned int* __restrict__ pack) {
    int e0 = blockIdx.x * 1024 + threadIdx.x * 4;
    if (e0 >= N_EDGES) return;
    int sh = blockIdx.x & 7;
    int4 d = *(const int4*)(dst + e0);
    int4 s = *(const int4*)(src + e0);
    int i0 = ((d.x >> 5) << 3) | sh;
    int i1 = ((d.y >> 5) << 3) | sh;
    int i2 = ((d.z >> 5) << 3) | sh;
    int i3 = ((d.w >> 5) << 3) | sh;
    int p0 = atomicAdd(cursor + i0, 1);
    int p1 = atomicAdd(cursor + i1, 1);
    int p2 = atomicAdd(cursor + i2, 1);
    int p3 = atomicAdd(cursor + i3, 1);
    if (p0 < ((i0 + 1) << 7)) pack[p0] = ((unsigned int)(d.x & 31) << 17) | (unsigned int)s.x;
    if (p1 < ((i1 + 1) << 7)) pack[p1] = ((unsigned int)(d.y & 31) << 17) | (unsigned int)s.y;
    if (p2 < ((i2 + 1) << 7)) pack[p2] = ((unsigned int)(d.z & 31) << 17) | (unsigned int)s.z;
    if (p3 < ((i3 + 1) << 7)) pack[p3] = ((unsigned int)(d.w & 31) << 17) | (unsigned int)s.w;
}

// ---------------------------------------------------------------------------
// 3) FUSED layer: one block per partition (32 nodes).
//    Stage: copy 8 slab segments into LDS + per-node histogram.
//    Phase A: LDS counting sort + register gather -> mean in LDS tile.
//    Phase B: MFMA GEMM h = relu([self | mean] @ W + b).
//    OUTPROJ: restage h tile in LDS, phase C MFMA out = h @ Wout + bout (fp32).
// ---------------------------------------------------------------------------
template <bool OUTPROJ>
__global__ __launch_bounds__(256) void fused_k(const unsigned short* __restrict__ xin,
                                               const unsigned int* __restrict__ pack,
                                               const int* __restrict__ cursor,
                                               const short8* __restrict__ wp,
                                               const float* __restrict__ bias,
                                               unsigned short* __restrict__ xout,
                                               const short8* __restrict__ wpo,
                                               const float* __restrict__ bout,
                                               float* __restrict__ outp) {
    __shared__ unsigned int eraw[CAPT];
    __shared__ unsigned int ssrc[CAPT];
    __shared__ int scnt[8];
    __shared__ int soff[9];
    __shared__ int bcnt[32];
    __shared__ int boff[33];
    __shared__ unsigned short mlds[PART_NODES][136];   // stride 272 B

    const int t = threadIdx.x;
    const int p = blockIdx.x;

    if (t < 8) {
        int idx = (p << 3) + t;
        int c = cursor[idx] - (idx << 7);
        scnt[t] = (c < CAP_SH) ? c : CAP_SH;
    }
    if (t < 32) bcnt[t] = 0;
    __syncthreads();
    if (t == 0) {
        int s = 0;
        #pragma unroll
        for (int i = 0; i < 8; ++i) { soff[i] = s; s += scnt[i]; }
        soff[8] = s;
    }
    __syncthreads();

    // stage 8 slab segments contiguously + per-node histogram
    #pragma unroll
    for (int sh = 0; sh < 8; ++sh) {
        int c = scnt[sh];
        int o = soff[sh];
        const unsigned int* gsrc = pack + ((size_t)((p << 3) + sh) << 7);
        for (int i = t; i < c; i += 256) {
            unsigned int pk = gsrc[i];
            eraw[o + i] = pk;
            atomicAdd(&bcnt[pk >> 17], 1);
        }
    }
    __syncthreads();

    const int n = soff[8];
    if (t == 0) {
        int s = 0;
        #pragma unroll
        for (int i = 0; i < 32; ++i) { boff[i] = s; s += bcnt[i]; }
        boff[32] = s;
    }
    __syncthreads();
    if (t < 32) bcnt[t] = boff[t];             // reuse as cursor
    __syncthreads();

    for (int i = t; i < n; i += 256) {
        unsigned int pk = eraw[i];
        int pos = atomicAdd(&bcnt[pk >> 17], 1);
        ssrc[pos] = pk & 0x1ffffu;
    }
    __syncthreads();

    // ---- phase A: gather into mlds ----
    const int w = t >> 6, lane = t & 63;
    const int sub = lane >> 4;                 // edge slot 0..3
    const int cl = lane & 15;                  // column group (cols cl*8..+7)

    for (int g = 0; g < 8; ++g) {
        const int ni = w * 8 + g;
        const int b = boff[ni];
        const int eN = boff[ni + 1];

        float acc[8];
        #pragma unroll
        for (int r = 0; r < 8; ++r) acc[r] = 0.f;

        for (int i = b + sub; i < eN; i += 4) {
            int s = ssrc[i];
            uint4 u = *(const uint4*)(xin + (size_t)s * 128 + cl * 8);
            acc[0] += bf2f(u.x & 0xffffu); acc[1] += bf2f(u.x >> 16);
            acc[2] += bf2f(u.y & 0xffffu); acc[3] += bf2f(u.y >> 16);
            acc[4] += bf2f(u.z & 0xffffu); acc[5] += bf2f(u.z >> 16);
            acc[6] += bf2f(u.w & 0xffffu); acc[7] += bf2f(u.w >> 16);
        }
        #pragma unroll
        for (int r = 0; r < 8; ++r) {
            acc[r] += __shfl_xor(acc[r], 16);
            acc[r] += __shfl_xor(acc[r], 32);
        }
        float inv = 1.0f / fmaxf((float)(eN - b), 1.0f);
        float lo = acc[sub * 2 + 0] * inv;
        float hi = acc[sub * 2 + 1] * inv;
        unsigned int o = ((unsigned int)f2bf(hi) << 16) | (unsigned int)f2bf(lo);
        *(unsigned int*)(&mlds[ni][cl * 8 + sub * 2]) = o;
    }
    __syncthreads();

    // ---- phase B: 32-row GEMM, K=256 (self 0..127 global, mean 128..255 LDS) ----
    const int frag = w & 1;                    // 16-row fragment 0/1
    const int cg0 = (w >> 1) * 4;              // col-tile group base (of 8)
    const int r15 = lane & 15;
    const int khi = lane >> 4;                 // 0..3
    const int row0 = p * PART_NODES + frag * 16;
    const unsigned short* arow = xin + (size_t)(row0 + r15) * 128 + khi * 8;

    f32x4 acc[4];
    #pragma unroll
    for (int c = 0; c < 4; ++c) acc[c] = {0.f, 0.f, 0.f, 0.f};

    #pragma unroll
    for (int ks = 0; ks < 8; ++ks) {
        short8 a;
        if (ks < 4) a = *(const short8*)(arow + ks * 32);
        else        a = *(const short8*)(&mlds[frag * 16 + r15][(ks - 4) * 32 + khi * 8]);
        #pragma unroll
        for (int c = 0; c < 4; ++c) {
            short8 b = wp[(ks * 8 + cg0 + c) * 64 + lane];
            acc[c] = __builtin_amdgcn_mfma_f32_16x16x32_bf16(a, b, acc[c], 0, 0, 0);
        }
    }

    const int rhi = khi, col0 = r15;
    if (!OUTPROJ) {
        #pragma unroll
        for (int c = 0; c < 4; ++c) {
            float bv = bias[(cg0 + c) * 16 + col0];
            #pragma unroll
            for (int j = 0; j < 4; ++j) {
                float v = fmaxf(acc[c][j] + bv, 0.f);
                xout[(size_t)(row0 + rhi * 4 + j) * 128 + (cg0 + c) * 16 + col0] = f2bf(v);
            }
        }
    } else {
        __syncthreads();                        // all mlds reads done
        // restage h tile (bias+relu) into mlds as bf16
        #pragma unroll
        for (int c = 0; c < 4; ++c) {
            float bv = bias[(cg0 + c) * 16 + col0];
            #pragma unroll
            for (int j = 0; j < 4; ++j) {
                float v = fmaxf(acc[c][j] + bv, 0.f);
                mlds[frag * 16 + rhi * 4 + j][(cg0 + c) * 16 + col0] = f2bf(v);
            }
        }
        __syncthreads();
        // ---- phase C: out[32 x 64] = h[32 x 128] @ Wout + bout ----
        const int frag2 = w & 1;
        const int ct0 = (w >> 1) * 2;          // 2 col-tiles of 4
        f32x4 oacc[2];
        oacc[0] = {0.f, 0.f, 0.f, 0.f};
        oacc[1] = {0.f, 0.f, 0.f, 0.f};
        #pragma unroll
        for (int ks = 0; ks < 4; ++ks) {
            short8 a = *(const short8*)(&mlds[frag2 * 16 + r15][ks * 32 + khi * 8]);
            #pragma unroll
            for (int c = 0; c < 2; ++c) {
                short8 b = wpo[(ks * 4 + ct0 + c) * 64 + lane];
                oacc[c] = __builtin_amdgcn_mfma_f32_16x16x32_bf16(a, b, oacc[c], 0, 0, 0);
            }
        }
        #pragma unroll
        for (int c = 0; c < 2; ++c) {
            float bv = bout[(ct0 + c) * 16 + col0];
            #pragma unroll
            for (int j = 0; j < 4; ++j) {
                outp[(size_t)(p * PART_NODES + frag2 * 16 + rhi * 4 + j) * N_CLASSES
                     + (ct0 + c) * 16 + col0] = oacc[c][j] + bv;
            }
        }
    }
}

// ---------------------------------------------------------------------------
extern "C" void kernel_launch(void* const* d_in, const int* in_sizes, int n_in,
                              void* d_out, int out_size, void* d_ws, size_t ws_size,
                              hipStream_t stream) {
    const float* feat   = (const float*)d_in[0];
    const int*   src    = (const int*)d_in[1];
    const int*   dst    = (const int*)d_in[2];
    const float* Wself1 = (const float*)d_in[3];
    const float* Wneigh1= (const float*)d_in[4];
    const float* b1     = (const float*)d_in[5];
    const float* Wself2 = (const float*)d_in[6];
    const float* Wneigh2= (const float*)d_in[7];
    const float* b2     = (const float*)d_in[8];
    const float* Wout   = (const float*)d_in[9];
    const float* bout   = (const float*)d_in[10];
    float* out = (float*)d_out;
    (void)ws_size;

    // workspace layout
    int* cursor = (int*)d_ws;                                     // 25000 (pad 8)
    unsigned int* pack = (unsigned int*)(cursor + NCTR + 8);      // 3.2M slabs
    unsigned short* fbuf1 = (unsigned short*)(pack + (size_t)NCTR * CAP_SH);
    unsigned short* h1    = fbuf1 + (size_t)N_NODES * D;          // N*128 bf16
    unsigned short* wp1   = h1 + (size_t)N_NODES * D;             // 256*128
    unsigned short* wp2   = wp1 + 256 * 128;
    unsigned short* wpo   = wp2 + 256 * 128;                      // 128*64

    // ---- prep: cursor init ∥ cvt ∥ weight pack ----
    prep_k<<<CIB + CVTB + PKB, 256, 0, stream>>>(cursor, feat, fbuf1,
                                                 Wself1, Wneigh1, Wself2, Wneigh2,
                                                 Wout, wp1, wp2, wpo);

    // ---- bin ----
    bin_k<<<EB, 256, 0, stream>>>(src, dst, cursor, pack);

    // ---- layer 1 (fused gather+GEMM) ----
    fused_k<false><<<NPART, 256, 0, stream>>>(fbuf1, pack, cursor,
                                              (const short8*)wp1, b1, h1,
                                              nullptr, nullptr, nullptr);

    // ---- layer 2 + output projection ----
    fused_k<true><<<NPART, 256, 0, stream>>>(h1, pack, cursor,
                                             (const short8*)wp2, b2, nullptr,
                                             (const short8*)wpo, bout, out);
}

// Round 10
// 255.589 us; speedup vs baseline: 1.8694x; 1.1686x over previous
//
#include <hip/hip_runtime.h>
#include <hip/hip_bf16.h>

constexpr int N_NODES = 100000;
constexpr int N_EDGES = 1600000;
constexpr int D = 128;
constexpr int N_CLASSES = 64;

constexpr int PART_NODES = 32;                 // nodes per partition
constexpr int NPART = N_NODES / PART_NODES;    // 3125 (exact)
constexpr int NCTR = NPART * 8;                // 25000 (8 shards)
constexpr int CAP_SH = 128;                    // slab entries per (part,shard)
constexpr int CAPT = 8 * CAP_SH;               // 1024 per partition
constexpr int EB = (N_EDGES + 1023) / 1024;    // 1563 bin blocks
constexpr int CIB = (NCTR + 255) / 256;        // 98 cursor-init blocks
constexpr int CVTB = N_NODES * (D / 4) / 256;  // 12500 cvt blocks (exact)
constexpr int PKB = 36;                        // 144 weight tiles / 4 per block
constexpr int H8B = N_NODES * D / 8 / 256;     // 6250 h1->fp8 blocks (exact)

typedef __attribute__((ext_vector_type(8))) short short8;
typedef __attribute__((ext_vector_type(4))) float f32x4;
typedef __attribute__((ext_vector_type(2))) float f32x2;

static __device__ __forceinline__ float bf2f(unsigned int lo16) {
    unsigned int x = lo16 << 16;
    return __builtin_bit_cast(float, x);
}
static __device__ __forceinline__ unsigned short f2bf(float f) {
    unsigned int x = __builtin_bit_cast(unsigned int, f);
    x += 0x7fffu + ((x >> 16) & 1u);          // RNE
    return (unsigned short)(x >> 16);
}
static __device__ __forceinline__ unsigned int pack4_fp8(float a, float b,
                                                         float c, float d) {
    int v = __builtin_amdgcn_cvt_pk_fp8_f32(a, b, 0, false);   // low word
    v = __builtin_amdgcn_cvt_pk_fp8_f32(c, d, v, true);        // high word
    return (unsigned int)v;
}

// ---------------------------------------------------------------------------
// 1) prep: cursor init (slab bases) ∥ feat fp32->bf16+fp8 ∥ weight packing
// ---------------------------------------------------------------------------
__global__ __launch_bounds__(256) void prep_k(int* __restrict__ cursor,
                                              const float* __restrict__ feat,
                                              unsigned short* __restrict__ fbuf,
                                              unsigned int* __restrict__ f8buf,
                                              const float* __restrict__ Ws1,
                                              const float* __restrict__ Wn1,
                                              const float* __restrict__ Ws2,
                                              const float* __restrict__ Wn2,
                                              const float* __restrict__ Wo,
                                              unsigned short* __restrict__ wp1,
                                              unsigned short* __restrict__ wp2,
                                              unsigned short* __restrict__ wpo) {
    const int b = blockIdx.x;
    const int t = threadIdx.x;
    if (b < CIB) {
        int i = b * 256 + t;
        if (i < NCTR) cursor[i] = i << 7;      // i * CAP_SH
    } else if (b < CIB + CVTB) {
        int i = (b - CIB) * 256 + t;           // float4 chunk id, 3.2M exact
        float4 v = ((const float4*)feat)[i];
        ushort4 r;
        r.x = f2bf(v.x); r.y = f2bf(v.y); r.z = f2bf(v.z); r.w = f2bf(v.w);
        ((ushort4*)fbuf)[i] = r;
        f8buf[i] = pack4_fp8(v.x, v.y, v.z, v.w);
    } else {
        int g = (b - CIB - CVTB) * 4 + (t >> 6);   // weight tile 0..143
        if (g >= 144) return;
        int lane = t & 63;
        const float *Wa, *Wb;
        unsigned short* wp;
        int DOUT, bb;
        if (g < 64)       { Wa = Ws1; Wb = Wn1; wp = wp1; DOUT = 128; bb = g; }
        else if (g < 128) { Wa = Ws2; Wb = Wn2; wp = wp2; DOUT = 128; bb = g - 64; }
        else              { Wa = Wo;  Wb = nullptr; wp = wpo; DOUT = 64; bb = g - 128; }
        int NCT = DOUT / 16;
        int kstep = bb / NCT;
        int ct = bb % NCT;
        int col = ct * 16 + (lane & 15);
        int kbase = kstep * 32 + (lane >> 4) * 8;
        unsigned short r[8];
        #pragma unroll
        for (int j = 0; j < 8; ++j) {
            int k = kbase + j;
            float w = (k < 128) ? Wa[(size_t)k * DOUT + col]
                                : Wb[(size_t)(k - 128) * DOUT + col];
            r[j] = f2bf(w);
        }
        *(short8*)(wp + ((size_t)((kstep * NCT + ct) * 64 + lane)) * 8) =
            *(const short8*)r;
    }
}

// ---------------------------------------------------------------------------
// 2) bin: append packed (dst_local<<17 | src) into fixed slabs.
// ---------------------------------------------------------------------------
__global__ __launch_bounds__(256) void bin_k(const int* __restrict__ src,
                                             const int* __restrict__ dst,
                                             int* __restrict__ cursor,
                                             unsigned int* __restrict__ pack) {
    int e0 = blockIdx.x * 1024 + threadIdx.x * 4;
    if (e0 >= N_EDGES) return;
    int sh = blockIdx.x & 7;
    int4 d = *(const int4*)(dst + e0);
    int4 s = *(const int4*)(src + e0);
    int i0 = ((d.x >> 5) << 3) | sh;
    int i1 = ((d.y >> 5) << 3) | sh;
    int i2 = ((d.z >> 5) << 3) | sh;
    int i3 = ((d.w >> 5) << 3) | sh;
    int p0 = atomicAdd(cursor + i0, 1);
    int p1 = atomicAdd(cursor + i1, 1);
    int p2 = atomicAdd(cursor + i2, 1);
    int p3 = atomicAdd(cursor + i3, 1);
    if (p0 < ((i0 + 1) << 7)) pack[p0] = ((unsigned int)(d.x & 31) << 17) | (unsigned int)s.x;
    if (p1 < ((i1 + 1) << 7)) pack[p1] = ((unsigned int)(d.y & 31) << 17) | (unsigned int)s.y;
    if (p2 < ((i2 + 1) << 7)) pack[p2] = ((unsigned int)(d.z & 31) << 17) | (unsigned int)s.z;
    if (p3 < ((i3 + 1) << 7)) pack[p3] = ((unsigned int)(d.w & 31) << 17) | (unsigned int)s.w;
}

// ---------------------------------------------------------------------------
// h1 bf16 -> fp8 shadow copy (between layer 1 and layer 2)
// ---------------------------------------------------------------------------
__global__ __launch_bounds__(256) void h1cvt_k(const unsigned int* __restrict__ h1u,
                                               unsigned int* __restrict__ h1f8) {
    int i = blockIdx.x * 256 + threadIdx.x;    // 8-col granule, 1.6M exact
    uint4 u = *((const uint4*)h1u + i);
    float f0 = bf2f(u.x & 0xffffu), f1 = bf2f(u.x >> 16);
    float f2 = bf2f(u.y & 0xffffu), f3 = bf2f(u.y >> 16);
    float f4 = bf2f(u.z & 0xffffu), f5 = bf2f(u.z >> 16);
    float f6 = bf2f(u.w & 0xffffu), f7 = bf2f(u.w >> 16);
    uint2 o;
    o.x = pack4_fp8(f0, f1, f2, f3);
    o.y = pack4_fp8(f4, f5, f6, f7);
    *((uint2*)h1f8 + i) = o;
}

// ---------------------------------------------------------------------------
// 3) FUSED layer: one block per partition (32 nodes).
//    Stage: copy 8 slab segments into LDS + per-node histogram + counting sort.
//    Phase A: register gather from FP8 rows (uint2/lane, 16 lanes/row,
//             hw cvt_pk_f32_fp8 decode), shfl-fold, bf16 mean into LDS tile.
//    Phase B: MFMA GEMM h = relu([self | mean] @ W + b)  (self/W stay bf16).
//    OUTPROJ: restage h tile in LDS, phase C MFMA out = h @ Wout + bout (fp32).
// ---------------------------------------------------------------------------
template <bool OUTPROJ>
__global__ __launch_bounds__(256) void fused_k(const unsigned short* __restrict__ xin,
                                               const unsigned char* __restrict__ x8,
                                               const unsigned int* __restrict__ pack,
                                               const int* __restrict__ cursor,
                                               const short8* __restrict__ wp,
                                               const float* __restrict__ bias,
                                               unsigned short* __restrict__ xout,
                                               const short8* __restrict__ wpo,
                                               const float* __restrict__ bout,
                                               float* __restrict__ outp) {
    __shared__ unsigned int eraw[CAPT];
    __shared__ unsigned int ssrc[CAPT];
    __shared__ int scnt[8];
    __shared__ int soff[9];
    __shared__ int bcnt[32];
    __shared__ int boff[33];
    __shared__ unsigned short mlds[PART_NODES][136];   // stride 272 B

    const int t = threadIdx.x;
    const int p = blockIdx.x;

    if (t < 8) {
        int idx = (p << 3) + t;
        int c = cursor[idx] - (idx << 7);
        scnt[t] = (c < CAP_SH) ? c : CAP_SH;
    }
    if (t < 32) bcnt[t] = 0;
    __syncthreads();
    if (t == 0) {
        int s = 0;
        #pragma unroll
        for (int i = 0; i < 8; ++i) { soff[i] = s; s += scnt[i]; }
        soff[8] = s;
    }
    __syncthreads();

    // stage 8 slab segments contiguously + per-node histogram
    #pragma unroll
    for (int sh = 0; sh < 8; ++sh) {
        int c = scnt[sh];
        int o = soff[sh];
        const unsigned int* gsrc = pack + ((size_t)((p << 3) + sh) << 7);
        for (int i = t; i < c; i += 256) {
            unsigned int pk = gsrc[i];
            eraw[o + i] = pk;
            atomicAdd(&bcnt[pk >> 17], 1);
        }
    }
    __syncthreads();

    const int n = soff[8];
    if (t == 0) {
        int s = 0;
        #pragma unroll
        for (int i = 0; i < 32; ++i) { boff[i] = s; s += bcnt[i]; }
        boff[32] = s;
    }
    __syncthreads();
    if (t < 32) bcnt[t] = boff[t];             // reuse as cursor
    __syncthreads();

    for (int i = t; i < n; i += 256) {
        unsigned int pk = eraw[i];
        int pos = atomicAdd(&bcnt[pk >> 17], 1);
        ssrc[pos] = pk & 0x1ffffu;
    }
    __syncthreads();

    // ---- phase A: fp8 gather into mlds ----
    const int w = t >> 6, lane = t & 63;
    const int sub = lane >> 4;                 // edge slot 0..3
    const int cl = lane & 15;                  // column group (cols cl*8..+7)

    for (int g = 0; g < 8; ++g) {
        const int ni = w * 8 + g;
        const int b = boff[ni];
        const int eN = boff[ni + 1];

        float acc[8];
        #pragma unroll
        for (int r = 0; r < 8; ++r) acc[r] = 0.f;

        for (int i = b + sub; i < eN; i += 4) {
            int s = ssrc[i];
            uint2 u = *(const uint2*)(x8 + (size_t)s * 128 + cl * 8);
            f32x2 q;
            q = __builtin_amdgcn_cvt_pk_f32_fp8(u.x, false);
            acc[0] += q[0]; acc[1] += q[1];
            q = __builtin_amdgcn_cvt_pk_f32_fp8(u.x, true);
            acc[2] += q[0]; acc[3] += q[1];
            q = __builtin_amdgcn_cvt_pk_f32_fp8(u.y, false);
            acc[4] += q[0]; acc[5] += q[1];
            q = __builtin_amdgcn_cvt_pk_f32_fp8(u.y, true);
            acc[6] += q[0]; acc[7] += q[1];
        }
        #pragma unroll
        for (int r = 0; r < 8; ++r) {
            acc[r] += __shfl_xor(acc[r], 16);
            acc[r] += __shfl_xor(acc[r], 32);
        }
        float inv = 1.0f / fmaxf((float)(eN - b), 1.0f);
        float lo = acc[sub * 2 + 0] * inv;
        float hi = acc[sub * 2 + 1] * inv;
        unsigned int o = ((unsigned int)f2bf(hi) << 16) | (unsigned int)f2bf(lo);
        *(unsigned int*)(&mlds[ni][cl * 8 + sub * 2]) = o;
    }
    __syncthreads();

    // ---- phase B: 32-row GEMM, K=256 (self 0..127 global bf16, mean LDS) ----
    const int frag = w & 1;                    // 16-row fragment 0/1
    const int cg0 = (w >> 1) * 4;              // col-tile group base (of 8)
    const int r15 = lane & 15;
    const int khi = lane >> 4;                 // 0..3
    const int row0 = p * PART_NODES + frag * 16;
    const unsigned short* arow = xin + (size_t)(row0 + r15) * 128 + khi * 8;

    f32x4 acc[4];
    #pragma unroll
    for (int c = 0; c < 4; ++c) acc[c] = {0.f, 0.f, 0.f, 0.f};

    #pragma unroll
    for (int ks = 0; ks < 8; ++ks) {
        short8 a;
        if (ks < 4) a = *(const short8*)(arow + ks * 32);
        else        a = *(const short8*)(&mlds[frag * 16 + r15][(ks - 4) * 32 + khi * 8]);
        #pragma unroll
        for (int c = 0; c < 4; ++c) {
            short8 b = wp[(ks * 8 + cg0 + c) * 64 + lane];
            acc[c] = __builtin_amdgcn_mfma_f32_16x16x32_bf16(a, b, acc[c], 0, 0, 0);
        }
    }

    const int rhi = khi, col0 = r15;
    if (!OUTPROJ) {
        #pragma unroll
        for (int c = 0; c < 4; ++c) {
            float bv = bias[(cg0 + c) * 16 + col0];
            #pragma unroll
            for (int j = 0; j < 4; ++j) {
                float v = fmaxf(acc[c][j] + bv, 0.f);
                xout[(size_t)(row0 + rhi * 4 + j) * 128 + (cg0 + c) * 16 + col0] = f2bf(v);
            }
        }
    } else {
        __syncthreads();                        // all mlds reads done
        // restage h tile (bias+relu) into mlds as bf16
        #pragma unroll
        for (int c = 0; c < 4; ++c) {
            float bv = bias[(cg0 + c) * 16 + col0];
            #pragma unroll
            for (int j = 0; j < 4; ++j) {
                float v = fmaxf(acc[c][j] + bv, 0.f);
                mlds[frag * 16 + rhi * 4 + j][(cg0 + c) * 16 + col0] = f2bf(v);
            }
        }
        __syncthreads();
        // ---- phase C: out[32 x 64] = h[32 x 128] @ Wout + bout ----
        const int frag2 = w & 1;
        const int ct0 = (w >> 1) * 2;          // 2 col-tiles of 4
        f32x4 oacc[2];
        oacc[0] = {0.f, 0.f, 0.f, 0.f};
        oacc[1] = {0.f, 0.f, 0.f, 0.f};
        #pragma unroll
        for (int ks = 0; ks < 4; ++ks) {
            short8 a = *(const short8*)(&mlds[frag2 * 16 + r15][ks * 32 + khi * 8]);
            #pragma unroll
            for (int c = 0; c < 2; ++c) {
                short8 b = wpo[(ks * 4 + ct0 + c) * 64 + lane];
                oacc[c] = __builtin_amdgcn_mfma_f32_16x16x32_bf16(a, b, oacc[c], 0, 0, 0);
            }
        }
        #pragma unroll
        for (int c = 0; c < 2; ++c) {
            float bv = bout[(ct0 + c) * 16 + col0];
            #pragma unroll
            for (int j = 0; j < 4; ++j) {
                outp[(size_t)(p * PART_NODES + frag2 * 16 + rhi * 4 + j) * N_CLASSES
                     + (ct0 + c) * 16 + col0] = oacc[c][j] + bv;
            }
        }
    }
}

// ---------------------------------------------------------------------------
extern "C" void kernel_launch(void* const* d_in, const int* in_sizes, int n_in,
                              void* d_out, int out_size, void* d_ws, size_t ws_size,
                              hipStream_t stream) {
    const float* feat   = (const float*)d_in[0];
    const int*   src    = (const int*)d_in[1];
    const int*   dst    = (const int*)d_in[2];
    const float* Wself1 = (const float*)d_in[3];
    const float* Wneigh1= (const float*)d_in[4];
    const float* b1     = (const float*)d_in[5];
    const float* Wself2 = (const float*)d_in[6];
    const float* Wneigh2= (const float*)d_in[7];
    const float* b2     = (const float*)d_in[8];
    const float* Wout   = (const float*)d_in[9];
    const float* bout   = (const float*)d_in[10];
    float* out = (float*)d_out;
    (void)ws_size;

    // workspace layout (~90 MB)
    int* cursor = (int*)d_ws;                                     // 25008 ints
    unsigned int* pack = (unsigned int*)(cursor + NCTR + 8);      // 3.2M
    unsigned short* fbuf1 = (unsigned short*)(pack + (size_t)NCTR * CAP_SH);
    unsigned short* h1    = fbuf1 + (size_t)N_NODES * D;          // N*128 bf16
    unsigned int* f8feat  = (unsigned int*)(h1 + (size_t)N_NODES * D);   // N*32
    unsigned int* h1f8    = f8feat + (size_t)N_NODES * (D / 4);          // N*32
    unsigned short* wp1   = (unsigned short*)(h1f8 + (size_t)N_NODES * (D / 4));
    unsigned short* wp2   = wp1 + 256 * 128;
    unsigned short* wpo   = wp2 + 256 * 128;                      // 128*64

    // ---- prep: cursor init ∥ cvt (bf16+fp8) ∥ weight pack ----
    prep_k<<<CIB + CVTB + PKB, 256, 0, stream>>>(cursor, feat, fbuf1, f8feat,
                                                 Wself1, Wneigh1, Wself2, Wneigh2,
                                                 Wout, wp1, wp2, wpo);

    // ---- bin ----
    bin_k<<<EB, 256, 0, stream>>>(src, dst, cursor, pack);

    // ---- layer 1 (fused gather+GEMM, fp8 payload) ----
    fused_k<false><<<NPART, 256, 0, stream>>>(fbuf1, (const unsigned char*)f8feat,
                                              pack, cursor,
                                              (const short8*)wp1, b1, h1,
                                              nullptr, nullptr, nullptr);

    // ---- h1 -> fp8 shadow ----
    h1cvt_k<<<H8B, 256, 0, stream>>>((const unsigned int*)h1, h1f8);

    // ---- layer 2 + output projection (fp8 payload) ----
    fused_k<true><<<NPART, 256, 0, stream>>>(h1, (const unsigned char*)h1f8,
                                             pack, cursor,
                                             (const short8*)wp2, b2, nullptr,
                                             (const short8*)wpo, bout, out);
}

// Round 11
// 195.243 us; speedup vs baseline: 2.4472x; 1.3091x over previous
//
#include <hip/hip_runtime.h>
#include <hip/hip_bf16.h>

constexpr int N_NODES = 100000;
constexpr int N_EDGES = 1600000;
constexpr int D = 128;
constexpr int N_CLASSES = 64;

constexpr int PART_NODES = 32;                 // nodes per partition
constexpr int NPART = N_NODES / PART_NODES;    // 3125 (exact)
constexpr int NB1 = 49;                        // coarse buckets (2048 nodes)
constexpr int CAP1 = 40960;                    // entries per coarse bucket
                                               // (mean 32768, sigma 181 -> 45 sigma)
constexpr int SUBB = 10;                       // pass-B sub-blocks per bucket
constexpr int CHUNK = CAP1 / SUBB;             // 4096
constexpr int CAP2 = 1024;                     // per-partition slab (mean 512)
constexpr int NCTR2 = NB1 * 64;                // 3136 fine counters (3125 used)
constexpr int EB1 = (N_EDGES + 1023) / 1024;   // 1563 pass-A blocks
constexpr int CIB = 13;                        // cursor-init blocks (49+3136)
constexpr int CVTB = N_NODES * (D / 4) / 256;  // 12500 cvt blocks (exact)
constexpr int PKB = 36;                        // 144 weight tiles / 4 per block
constexpr int H8B = N_NODES * D / 8 / 256;     // 6250 h1->fp8 blocks (exact)

typedef __attribute__((ext_vector_type(8))) short short8;
typedef __attribute__((ext_vector_type(4))) float f32x4;
typedef __attribute__((ext_vector_type(2))) float f32x2;

static __device__ __forceinline__ float bf2f(unsigned int lo16) {
    unsigned int x = lo16 << 16;
    return __builtin_bit_cast(float, x);
}
static __device__ __forceinline__ unsigned short f2bf(float f) {
    unsigned int x = __builtin_bit_cast(unsigned int, f);
    x += 0x7fffu + ((x >> 16) & 1u);          // RNE
    return (unsigned short)(x >> 16);
}
static __device__ __forceinline__ unsigned int pack4_fp8(float a, float b,
                                                         float c, float d) {
    int v = __builtin_amdgcn_cvt_pk_fp8_f32(a, b, 0, false);   // low word
    v = __builtin_amdgcn_cvt_pk_fp8_f32(c, d, v, true);        // high word
    return (unsigned int)v;
}

// ---------------------------------------------------------------------------
// 1) prep: cursor1/cursor2 init ∥ feat fp32->bf16+fp8 ∥ weight packing
// ---------------------------------------------------------------------------
__global__ __launch_bounds__(256) void prep_k(int* __restrict__ cursor1,
                                              int* __restrict__ cursor2,
                                              const float* __restrict__ feat,
                                              unsigned short* __restrict__ fbuf,
                                              unsigned int* __restrict__ f8buf,
                                              const float* __restrict__ Ws1,
                                              const float* __restrict__ Wn1,
                                              const float* __restrict__ Ws2,
                                              const float* __restrict__ Wn2,
                                              const float* __restrict__ Wo,
                                              unsigned short* __restrict__ wp1,
                                              unsigned short* __restrict__ wp2,
                                              unsigned short* __restrict__ wpo) {
    const int b = blockIdx.x;
    const int t = threadIdx.x;
    if (b < CIB) {
        int i = b * 256 + t;
        if (i < NB1) cursor1[i] = i * CAP1;
        if (i < NCTR2) cursor2[i] = i << 10;   // i * CAP2
    } else if (b < CIB + CVTB) {
        int i = (b - CIB) * 256 + t;           // float4 chunk id, 3.2M exact
        float4 v = ((const float4*)feat)[i];
        ushort4 r;
        r.x = f2bf(v.x); r.y = f2bf(v.y); r.z = f2bf(v.z); r.w = f2bf(v.w);
        ((ushort4*)fbuf)[i] = r;
        f8buf[i] = pack4_fp8(v.x, v.y, v.z, v.w);
    } else {
        int g = (b - CIB - CVTB) * 4 + (t >> 6);   // weight tile 0..143
        if (g >= 144) return;
        int lane = t & 63;
        const float *Wa, *Wb;
        unsigned short* wp;
        int DOUT, bb;
        if (g < 64)       { Wa = Ws1; Wb = Wn1; wp = wp1; DOUT = 128; bb = g; }
        else if (g < 128) { Wa = Ws2; Wb = Wn2; wp = wp2; DOUT = 128; bb = g - 64; }
        else              { Wa = Wo;  Wb = nullptr; wp = wpo; DOUT = 64; bb = g - 128; }
        int NCT = DOUT / 16;
        int kstep = bb / NCT;
        int ct = bb % NCT;
        int col = ct * 16 + (lane & 15);
        int kbase = kstep * 32 + (lane >> 4) * 8;
        unsigned short r[8];
        #pragma unroll
        for (int j = 0; j < 8; ++j) {
            int k = kbase + j;
            float w = (k < 128) ? Wa[(size_t)k * DOUT + col]
                                : Wb[(size_t)(k - 128) * DOUT + col];
            r[j] = f2bf(w);
        }
        *(short8*)(wp + ((size_t)((kstep * NCT + ct) * 64 + lane)) * 8) =
            *(const short8*)r;
    }
}

// ---------------------------------------------------------------------------
// 2a) pass A: per-1024-edge block, LDS counting sort by coarse bucket
//     (cb = dst>>11, 49 buckets), bulk-reserve (49 atomics/block), write
//     sorted runs coalesced. payload1 = (dst&2047)<<17 | src   (28 bits).
// ---------------------------------------------------------------------------
__global__ __launch_bounds__(256) void bin1_k(const int* __restrict__ src,
                                              const int* __restrict__ dst,
                                              int* __restrict__ cursor1,
                                              unsigned int* __restrict__ pack1) {
    __shared__ unsigned int lpay[1024];
    __shared__ unsigned char lcb[1024];
    __shared__ int hist[NB1], loff[NB1], gpos[NB1], lcur[NB1];

    const int t = threadIdx.x;
    const int ebase = blockIdx.x * 1024;
    int nblk = N_EDGES - ebase;
    if (nblk > 1024) nblk = 1024;
    const bool ok = (t * 4 < nblk);

    if (t < NB1) hist[t] = 0;
    __syncthreads();

    int4 d4, s4;
    if (ok) {
        d4 = *(const int4*)(dst + ebase + t * 4);
        s4 = *(const int4*)(src + ebase + t * 4);
        atomicAdd(&hist[d4.x >> 11], 1);
        atomicAdd(&hist[d4.y >> 11], 1);
        atomicAdd(&hist[d4.z >> 11], 1);
        atomicAdd(&hist[d4.w >> 11], 1);
    }
    __syncthreads();

    if (t == 0) {
        int run = 0;
        #pragma unroll
        for (int b = 0; b < NB1; ++b) { loff[b] = run; run += hist[b]; }
    }
    __syncthreads();
    if (t < NB1) {
        gpos[t] = atomicAdd(cursor1 + t, hist[t]);
        lcur[t] = loff[t];
    }
    __syncthreads();

    if (ok) {
        #pragma unroll
        for (int k = 0; k < 4; ++k) {
            int dd = (k == 0) ? d4.x : (k == 1) ? d4.y : (k == 2) ? d4.z : d4.w;
            int ss = (k == 0) ? s4.x : (k == 1) ? s4.y : (k == 2) ? s4.z : s4.w;
            int cb = dd >> 11;
            int pos = atomicAdd(&lcur[cb], 1);
            lpay[pos] = ((unsigned int)(dd & 2047) << 17) | (unsigned int)ss;
            lcb[pos] = (unsigned char)cb;
        }
    }
    __syncthreads();

    for (int i = t; i < nblk; i += 256) {
        int cb = lcb[i];
        int op = gpos[cb] + (i - loff[cb]);
        if (op < (cb + 1) * CAP1) pack1[op] = lpay[i];
    }
}

// ---------------------------------------------------------------------------
// 2b) pass B: 49 buckets x 10 chunks of 4096. LDS counting sort by partition
//     within bucket (pw = pk>>22; global p = cb*64+pw == dst>>5), bulk-reserve
//     (64 atomics/block), write full-line runs. final payload = pk & 0x3fffff.
// ---------------------------------------------------------------------------
__global__ __launch_bounds__(256) void bin2_k(const int* __restrict__ cursor1,
                                              int* __restrict__ cursor2,
                                              const unsigned int* __restrict__ pack1,
                                              unsigned int* __restrict__ pack2) {
    __shared__ unsigned int lpay[CHUNK];       // 16 KB
    __shared__ unsigned int lsort[CHUNK];      // 16 KB
    __shared__ int hist[64], loff[64], gpos[64], lcur[64];

    const int t = threadIdx.x;
    const int cb = blockIdx.x / SUBB;
    const int sb = blockIdx.x % SUBB;

    int cnt = cursor1[cb] - cb * CAP1;
    if (cnt > CAP1) cnt = CAP1;
    const int base = sb * CHUNK;
    int n = cnt - base;
    if (n <= 0) return;
    if (n > CHUNK) n = CHUNK;

    if (t < 64) hist[t] = 0;
    __syncthreads();

    const unsigned int* gsrc = pack1 + (size_t)cb * CAP1 + base;
    for (int i = t; i < n; i += 256) {
        unsigned int pk = gsrc[i];
        lpay[i] = pk;
        atomicAdd(&hist[pk >> 22], 1);
    }
    __syncthreads();

    if (t == 0) {
        int run = 0;
        #pragma unroll
        for (int b = 0; b < 64; ++b) { loff[b] = run; run += hist[b]; }
    }
    __syncthreads();
    if (t < 64) {
        gpos[t] = atomicAdd(cursor2 + cb * 64 + t, hist[t]);
        lcur[t] = loff[t];
    }
    __syncthreads();

    for (int i = t; i < n; i += 256) {
        unsigned int pk = lpay[i];
        int pos = atomicAdd(&lcur[pk >> 22], 1);
        lsort[pos] = pk;
    }
    __syncthreads();

    for (int i = t; i < n; i += 256) {
        unsigned int pk = lsort[i];
        int pw = pk >> 22;
        int p = cb * 64 + pw;
        int op = gpos[pw] + (i - loff[pw]);
        if (op < ((p + 1) << 10)) pack2[op] = pk & 0x003fffffu;
    }
}

// ---------------------------------------------------------------------------
// h1 bf16 -> fp8 shadow copy (between layer 1 and layer 2)
// ---------------------------------------------------------------------------
__global__ __launch_bounds__(256) void h1cvt_k(const unsigned int* __restrict__ h1u,
                                               unsigned int* __restrict__ h1f8) {
    int i = blockIdx.x * 256 + threadIdx.x;    // 8-col granule, 1.6M exact
    uint4 u = *((const uint4*)h1u + i);
    float f0 = bf2f(u.x & 0xffffu), f1 = bf2f(u.x >> 16);
    float f2 = bf2f(u.y & 0xffffu), f3 = bf2f(u.y >> 16);
    float f4 = bf2f(u.z & 0xffffu), f5 = bf2f(u.z >> 16);
    float f6 = bf2f(u.w & 0xffffu), f7 = bf2f(u.w >> 16);
    uint2 o;
    o.x = pack4_fp8(f0, f1, f2, f3);
    o.y = pack4_fp8(f4, f5, f6, f7);
    *((uint2*)h1f8 + i) = o;
}

// ---------------------------------------------------------------------------
// 3) FUSED layer: one block per partition (32 nodes).
//    Stage: read contiguous slab [p*CAP2, +scnt) + per-node counting sort.
//    Phase A: fp8 register gather (uint2/lane, hw cvt decode), shfl-fold,
//             bf16 mean into LDS tile.
//    Phase B: MFMA GEMM h = relu([self | mean] @ W + b)  (bf16).
//    OUTPROJ: restage h tile in LDS, phase C MFMA out = h @ Wout + bout (fp32).
// ---------------------------------------------------------------------------
template <bool OUTPROJ>
__global__ __launch_bounds__(256) void fused_k(const unsigned short* __restrict__ xin,
                                               const unsigned char* __restrict__ x8,
                                               const unsigned int* __restrict__ pack,
                                               const int* __restrict__ cursor2,
                                               const short8* __restrict__ wp,
                                               const float* __restrict__ bias,
                                               unsigned short* __restrict__ xout,
                                               const short8* __restrict__ wpo,
                                               const float* __restrict__ bout,
                                               float* __restrict__ outp) {
    __shared__ unsigned int eraw[CAP2];
    __shared__ unsigned int ssrc[CAP2];
    __shared__ int nsh;
    __shared__ int bcnt[32];
    __shared__ int boff[33];
    __shared__ unsigned short mlds[PART_NODES][136];   // stride 272 B

    const int t = threadIdx.x;
    const int p = blockIdx.x;

    if (t == 0) {
        int c = cursor2[p] - (p << 10);
        nsh = (c < CAP2) ? c : CAP2;
    }
    if (t < 32) bcnt[t] = 0;
    __syncthreads();
    const int n = nsh;

    // stage slab + per-node histogram
    const unsigned int* gsrc = pack + ((size_t)p << 10);
    for (int i = t; i < n; i += 256) {
        unsigned int pk = gsrc[i];
        eraw[i] = pk;
        atomicAdd(&bcnt[pk >> 17], 1);
    }
    __syncthreads();

    if (t == 0) {
        int s = 0;
        #pragma unroll
        for (int i = 0; i < 32; ++i) { boff[i] = s; s += bcnt[i]; }
        boff[32] = s;
    }
    __syncthreads();
    if (t < 32) bcnt[t] = boff[t];             // reuse as cursor
    __syncthreads();

    for (int i = t; i < n; i += 256) {
        unsigned int pk = eraw[i];
        int pos = atomicAdd(&bcnt[pk >> 17], 1);
        ssrc[pos] = pk & 0x1ffffu;
    }
    __syncthreads();

    // ---- phase A: fp8 gather into mlds ----
    const int w = t >> 6, lane = t & 63;
    const int sub = lane >> 4;                 // edge slot 0..3
    const int cl = lane & 15;                  // column group (cols cl*8..+7)

    for (int g = 0; g < 8; ++g) {
        const int ni = w * 8 + g;
        const int b = boff[ni];
        const int eN = boff[ni + 1];

        float acc[8];
        #pragma unroll
        for (int r = 0; r < 8; ++r) acc[r] = 0.f;

        for (int i = b + sub; i < eN; i += 4) {
            int s = ssrc[i];
            uint2 u = *(const uint2*)(x8 + (size_t)s * 128 + cl * 8);
            f32x2 q;
            q = __builtin_amdgcn_cvt_pk_f32_fp8(u.x, false);
            acc[0] += q[0]; acc[1] += q[1];
            q = __builtin_amdgcn_cvt_pk_f32_fp8(u.x, true);
            acc[2] += q[0]; acc[3] += q[1];
            q = __builtin_amdgcn_cvt_pk_f32_fp8(u.y, false);
            acc[4] += q[0]; acc[5] += q[1];
            q = __builtin_amdgcn_cvt_pk_f32_fp8(u.y, true);
            acc[6] += q[0]; acc[7] += q[1];
        }
        #pragma unroll
        for (int r = 0; r < 8; ++r) {
            acc[r] += __shfl_xor(acc[r], 16);
            acc[r] += __shfl_xor(acc[r], 32);
        }
        float inv = 1.0f / fmaxf((float)(eN - b), 1.0f);
        float lo = acc[sub * 2 + 0] * inv;
        float hi = acc[sub * 2 + 1] * inv;
        unsigned int o = ((unsigned int)f2bf(hi) << 16) | (unsigned int)f2bf(lo);
        *(unsigned int*)(&mlds[ni][cl * 8 + sub * 2]) = o;
    }
    __syncthreads();

    // ---- phase B: 32-row GEMM, K=256 (self 0..127 global bf16, mean LDS) ----
    const int frag = w & 1;                    // 16-row fragment 0/1
    const int cg0 = (w >> 1) * 4;              // col-tile group base (of 8)
    const int r15 = lane & 15;
    const int khi = lane >> 4;                 // 0..3
    const int row0 = p * PART_NODES + frag * 16;
    const unsigned short* arow = xin + (size_t)(row0 + r15) * 128 + khi * 8;

    f32x4 acc[4];
    #pragma unroll
    for (int c = 0; c < 4; ++c) acc[c] = {0.f, 0.f, 0.f, 0.f};

    #pragma unroll
    for (int ks = 0; ks < 8; ++ks) {
        short8 a;
        if (ks < 4) a = *(const short8*)(arow + ks * 32);
        else        a = *(const short8*)(&mlds[frag * 16 + r15][(ks - 4) * 32 + khi * 8]);
        #pragma unroll
        for (int c = 0; c < 4; ++c) {
            short8 b = wp[(ks * 8 + cg0 + c) * 64 + lane];
            acc[c] = __builtin_amdgcn_mfma_f32_16x16x32_bf16(a, b, acc[c], 0, 0, 0);
        }
    }

    const int rhi = khi, col0 = r15;
    if (!OUTPROJ) {
        #pragma unroll
        for (int c = 0; c < 4; ++c) {
            float bv = bias[(cg0 + c) * 16 + col0];
            #pragma unroll
            for (int j = 0; j < 4; ++j) {
                float v = fmaxf(acc[c][j] + bv, 0.f);
                xout[(size_t)(row0 + rhi * 4 + j) * 128 + (cg0 + c) * 16 + col0] = f2bf(v);
            }
        }
    } else {
        __syncthreads();                        // all mlds reads done
        // restage h tile (bias+relu) into mlds as bf16
        #pragma unroll
        for (int c = 0; c < 4; ++c) {
            float bv = bias[(cg0 + c) * 16 + col0];
            #pragma unroll
            for (int j = 0; j < 4; ++j) {
                float v = fmaxf(acc[c][j] + bv, 0.f);
                mlds[frag * 16 + rhi * 4 + j][(cg0 + c) * 16 + col0] = f2bf(v);
            }
        }
        __syncthreads();
        // ---- phase C: out[32 x 64] = h[32 x 128] @ Wout + bout ----
        const int frag2 = w & 1;
        const int ct0 = (w >> 1) * 2;          // 2 col-tiles of 4
        f32x4 oacc[2];
        oacc[0] = {0.f, 0.f, 0.f, 0.f};
        oacc[1] = {0.f, 0.f, 0.f, 0.f};
        #pragma unroll
        for (int ks = 0; ks < 4; ++ks) {
            short8 a = *(const short8*)(&mlds[frag2 * 16 + r15][ks * 32 + khi * 8]);
            #pragma unroll
            for (int c = 0; c < 2; ++c) {
                short8 b = wpo[(ks * 4 + ct0 + c) * 64 + lane];
                oacc[c] = __builtin_amdgcn_mfma_f32_16x16x32_bf16(a, b, oacc[c], 0, 0, 0);
            }
        }
        #pragma unroll
        for (int c = 0; c < 2; ++c) {
            float bv = bout[(ct0 + c) * 16 + col0];
            #pragma unroll
            for (int j = 0; j < 4; ++j) {
                outp[(size_t)(p * PART_NODES + frag2 * 16 + rhi * 4 + j) * N_CLASSES
                     + (ct0 + c) * 16 + col0] = oacc[c][j] + bv;
            }
        }
    }
}

// ---------------------------------------------------------------------------
extern "C" void kernel_launch(void* const* d_in, const int* in_sizes, int n_in,
                              void* d_out, int out_size, void* d_ws, size_t ws_size,
                              hipStream_t stream) {
    const float* feat   = (const float*)d_in[0];
    const int*   src    = (const int*)d_in[1];
    const int*   dst    = (const int*)d_in[2];
    const float* Wself1 = (const float*)d_in[3];
    const float* Wneigh1= (const float*)d_in[4];
    const float* b1     = (const float*)d_in[5];
    const float* Wself2 = (const float*)d_in[6];
    const float* Wneigh2= (const float*)d_in[7];
    const float* b2     = (const float*)d_in[8];
    const float* Wout   = (const float*)d_in[9];
    const float* bout   = (const float*)d_in[10];
    float* out = (float*)d_out;
    (void)ws_size;

    // workspace layout (~100 MB)
    int* cursor1 = (int*)d_ws;                                    // 49 (pad 64)
    int* cursor2 = cursor1 + 64;                                  // 3136
    unsigned int* pack1 = (unsigned int*)(cursor2 + NCTR2);       // 49*40960
    unsigned int* pack2 = pack1 + (size_t)NB1 * CAP1;             // 3136*1024
    unsigned short* fbuf1 = (unsigned short*)(pack2 + (size_t)NCTR2 * CAP2);
    unsigned short* h1    = fbuf1 + (size_t)N_NODES * D;          // N*128 bf16
    unsigned int* f8feat  = (unsigned int*)(h1 + (size_t)N_NODES * D);   // N*32
    unsigned int* h1f8    = f8feat + (size_t)N_NODES * (D / 4);          // N*32
    unsigned short* wp1   = (unsigned short*)(h1f8 + (size_t)N_NODES * (D / 4));
    unsigned short* wp2   = wp1 + 256 * 128;
    unsigned short* wpo   = wp2 + 256 * 128;                      // 128*64

    // ---- prep: cursor init ∥ cvt (bf16+fp8) ∥ weight pack ----
    prep_k<<<CIB + CVTB + PKB, 256, 0, stream>>>(cursor1, cursor2, feat,
                                                 fbuf1, f8feat,
                                                 Wself1, Wneigh1, Wself2, Wneigh2,
                                                 Wout, wp1, wp2, wpo);

    // ---- two-pass edge binning ----
    bin1_k<<<EB1, 256, 0, stream>>>(src, dst, cursor1, pack1);
    bin2_k<<<NB1 * SUBB, 256, 0, stream>>>(cursor1, cursor2, pack1, pack2);

    // ---- layer 1 (fused gather+GEMM, fp8 payload) ----
    fused_k<false><<<NPART, 256, 0, stream>>>(fbuf1, (const unsigned char*)f8feat,
                                              pack2, cursor2,
                                              (const short8*)wp1, b1, h1,
                                              nullptr, nullptr, nullptr);

    // ---- h1 -> fp8 shadow ----
    h1cvt_k<<<H8B, 256, 0, stream>>>((const unsigned int*)h1, h1f8);

    // ---- layer 2 + output projection (fp8 payload) ----
    fused_k<true><<<NPART, 256, 0, stream>>>(h1, (const unsigned char*)h1f8,
                                             pack2, cursor2,
                                             (const short8*)wp2, b2, nullptr,
                                             (const short8*)wpo, bout, out);
}

// Round 12
// 177.941 us; speedup vs baseline: 2.6852x; 1.0972x over previous
//
#include <hip/hip_runtime.h>
#include <hip/hip_bf16.h>

constexpr int N_NODES = 100000;
constexpr int N_EDGES = 1600000;
constexpr int D = 128;
constexpr int N_CLASSES = 64;

constexpr int PART_NODES = 32;                 // nodes per partition
constexpr int NPART = N_NODES / PART_NODES;    // 3125 (exact)
constexpr int NB1 = 49;                        // coarse buckets (2048 nodes)
constexpr int CAP1 = 40960;                    // entries per coarse bucket
constexpr int SUBB = 10;                       // pass-B sub-blocks per bucket
constexpr int CHUNK = CAP1 / SUBB;             // 4096
constexpr int CAP2 = 1024;                     // per-partition slab (mean 512)
constexpr int NCTR2 = NB1 * 64;                // 3136 fine counters (3125 used)
constexpr int EB1 = (N_EDGES + 1023) / 1024;   // 1563 pass-A blocks
constexpr int CIB = 13;                        // cursor-init blocks (49+3136)
constexpr int CVTB = N_NODES * (D / 4) / 256;  // 12500 cvt blocks (exact)
constexpr int PKB = 36;                        // 144 weight tiles / 4 per block

typedef __attribute__((ext_vector_type(8))) short short8;
typedef __attribute__((ext_vector_type(4))) float f32x4;
typedef __attribute__((ext_vector_type(2))) float f32x2;

static __device__ __forceinline__ float bf2f(unsigned int lo16) {
    unsigned int x = lo16 << 16;
    return __builtin_bit_cast(float, x);
}
static __device__ __forceinline__ unsigned short f2bf(float f) {
    unsigned int x = __builtin_bit_cast(unsigned int, f);
    x += 0x7fffu + ((x >> 16) & 1u);          // RNE
    return (unsigned short)(x >> 16);
}
static __device__ __forceinline__ unsigned int pack4_fp8(float a, float b,
                                                         float c, float d) {
    int v = __builtin_amdgcn_cvt_pk_fp8_f32(a, b, 0, false);   // low word
    v = __builtin_amdgcn_cvt_pk_fp8_f32(c, d, v, true);        // high word
    return (unsigned int)v;
}
static __device__ __forceinline__ unsigned char f2fp8(float a) {
    return (unsigned char)(__builtin_amdgcn_cvt_pk_fp8_f32(a, a, 0, false) & 0xff);
}

// ---------------------------------------------------------------------------
// 1) prep: cursor1/cursor2 init ∥ feat fp32->bf16+fp8 ∥ weight packing
// ---------------------------------------------------------------------------
__global__ __launch_bounds__(256) void prep_k(int* __restrict__ cursor1,
                                              int* __restrict__ cursor2,
                                              const float* __restrict__ feat,
                                              unsigned short* __restrict__ fbuf,
                                              unsigned int* __restrict__ f8buf,
                                              const float* __restrict__ Ws1,
                                              const float* __restrict__ Wn1,
                                              const float* __restrict__ Ws2,
                                              const float* __restrict__ Wn2,
                                              const float* __restrict__ Wo,
                                              unsigned short* __restrict__ wp1,
                                              unsigned short* __restrict__ wp2,
                                              unsigned short* __restrict__ wpo) {
    const int b = blockIdx.x;
    const int t = threadIdx.x;
    if (b < CIB) {
        int i = b * 256 + t;
        if (i < NB1) cursor1[i] = i * CAP1;
        if (i < NCTR2) cursor2[i] = i << 10;   // i * CAP2
    } else if (b < CIB + CVTB) {
        int i = (b - CIB) * 256 + t;           // float4 chunk id, 3.2M exact
        float4 v = ((const float4*)feat)[i];
        ushort4 r;
        r.x = f2bf(v.x); r.y = f2bf(v.y); r.z = f2bf(v.z); r.w = f2bf(v.w);
        ((ushort4*)fbuf)[i] = r;
        f8buf[i] = pack4_fp8(v.x, v.y, v.z, v.w);
    } else {
        int g = (b - CIB - CVTB) * 4 + (t >> 6);   // weight tile 0..143
        if (g >= 144) return;
        int lane = t & 63;
        const float *Wa, *Wb;
        unsigned short* wp;
        int DOUT, bb;
        if (g < 64)       { Wa = Ws1; Wb = Wn1; wp = wp1; DOUT = 128; bb = g; }
        else if (g < 128) { Wa = Ws2; Wb = Wn2; wp = wp2; DOUT = 128; bb = g - 64; }
        else              { Wa = Wo;  Wb = nullptr; wp = wpo; DOUT = 64; bb = g - 128; }
        int NCT = DOUT / 16;
        int kstep = bb / NCT;
        int ct = bb % NCT;
        int col = ct * 16 + (lane & 15);
        int kbase = kstep * 32 + (lane >> 4) * 8;
        unsigned short r[8];
        #pragma unroll
        for (int j = 0; j < 8; ++j) {
            int k = kbase + j;
            float w = (k < 128) ? Wa[(size_t)k * DOUT + col]
                                : Wb[(size_t)(k - 128) * DOUT + col];
            r[j] = f2bf(w);
        }
        *(short8*)(wp + ((size_t)((kstep * NCT + ct) * 64 + lane)) * 8) =
            *(const short8*)r;
    }
}

// ---------------------------------------------------------------------------
// 2a) pass A: LDS counting sort by coarse bucket (cb = dst>>11), bulk-reserve,
//     coalesced run writes. payload1 = (dst&2047)<<17 | src  (28 bits).
// ---------------------------------------------------------------------------
__global__ __launch_bounds__(256) void bin1_k(const int* __restrict__ src,
                                              const int* __restrict__ dst,
                                              int* __restrict__ cursor1,
                                              unsigned int* __restrict__ pack1) {
    __shared__ unsigned int lpay[1024];
    __shared__ unsigned char lcb[1024];
    __shared__ int hist[NB1], loff[NB1], gpos[NB1], lcur[NB1];

    const int t = threadIdx.x;
    const int ebase = blockIdx.x * 1024;
    int nblk = N_EDGES - ebase;
    if (nblk > 1024) nblk = 1024;
    const bool ok = (t * 4 < nblk);

    if (t < NB1) hist[t] = 0;
    __syncthreads();

    int4 d4, s4;
    if (ok) {
        d4 = *(const int4*)(dst + ebase + t * 4);
        s4 = *(const int4*)(src + ebase + t * 4);
        atomicAdd(&hist[d4.x >> 11], 1);
        atomicAdd(&hist[d4.y >> 11], 1);
        atomicAdd(&hist[d4.z >> 11], 1);
        atomicAdd(&hist[d4.w >> 11], 1);
    }
    __syncthreads();

    if (t == 0) {
        int run = 0;
        #pragma unroll
        for (int b = 0; b < NB1; ++b) { loff[b] = run; run += hist[b]; }
    }
    __syncthreads();
    if (t < NB1) {
        gpos[t] = atomicAdd(cursor1 + t, hist[t]);
        lcur[t] = loff[t];
    }
    __syncthreads();

    if (ok) {
        #pragma unroll
        for (int k = 0; k < 4; ++k) {
            int dd = (k == 0) ? d4.x : (k == 1) ? d4.y : (k == 2) ? d4.z : d4.w;
            int ss = (k == 0) ? s4.x : (k == 1) ? s4.y : (k == 2) ? s4.z : s4.w;
            int cb = dd >> 11;
            int pos = atomicAdd(&lcur[cb], 1);
            lpay[pos] = ((unsigned int)(dd & 2047) << 17) | (unsigned int)ss;
            lcb[pos] = (unsigned char)cb;
        }
    }
    __syncthreads();

    for (int i = t; i < nblk; i += 256) {
        int cb = lcb[i];
        int op = gpos[cb] + (i - loff[cb]);
        if (op < (cb + 1) * CAP1) pack1[op] = lpay[i];
    }
}

// ---------------------------------------------------------------------------
// 2b) pass B: sort each coarse-bucket chunk by partition (pw = pk>>22),
//     bulk-reserve, full-line run writes. final payload = pk & 0x3fffff.
// ---------------------------------------------------------------------------
__global__ __launch_bounds__(256) void bin2_k(const int* __restrict__ cursor1,
                                              int* __restrict__ cursor2,
                                              const unsigned int* __restrict__ pack1,
                                              unsigned int* __restrict__ pack2) {
    __shared__ unsigned int lpay[CHUNK];       // 16 KB
    __shared__ unsigned int lsort[CHUNK];      // 16 KB
    __shared__ int hist[64], loff[64], gpos[64], lcur[64];

    const int t = threadIdx.x;
    const int cb = blockIdx.x / SUBB;
    const int sb = blockIdx.x % SUBB;

    int cnt = cursor1[cb] - cb * CAP1;
    if (cnt > CAP1) cnt = CAP1;
    const int base = sb * CHUNK;
    int n = cnt - base;
    if (n <= 0) return;
    if (n > CHUNK) n = CHUNK;

    if (t < 64) hist[t] = 0;
    __syncthreads();

    const unsigned int* gsrc = pack1 + (size_t)cb * CAP1 + base;
    for (int i = t; i < n; i += 256) {
        unsigned int pk = gsrc[i];
        lpay[i] = pk;
        atomicAdd(&hist[pk >> 22], 1);
    }
    __syncthreads();

    if (t == 0) {
        int run = 0;
        #pragma unroll
        for (int b = 0; b < 64; ++b) { loff[b] = run; run += hist[b]; }
    }
    __syncthreads();
    if (t < 64) {
        gpos[t] = atomicAdd(cursor2 + cb * 64 + t, hist[t]);
        lcur[t] = loff[t];
    }
    __syncthreads();

    for (int i = t; i < n; i += 256) {
        unsigned int pk = lpay[i];
        int pos = atomicAdd(&lcur[pk >> 22], 1);
        lsort[pos] = pk;
    }
    __syncthreads();

    for (int i = t; i < n; i += 256) {
        unsigned int pk = lsort[i];
        int pw = pk >> 22;
        int p = cb * 64 + pw;
        int op = gpos[pw] + (i - loff[pw]);
        if (op < ((p + 1) << 10)) pack2[op] = pk & 0x003fffffu;
    }
}

// ---------------------------------------------------------------------------
// 3) FUSED layer: one block per partition (32 nodes).
//    Stage slab + per-node counting sort; fp8 register gather with 8 edge
//    loads in flight (2x unrolled pairs); bf16 mean into LDS; MFMA GEMM.
//    !OUTPROJ: epilogue writes bf16 h AND its fp8 shadow (for next layer).
//    OUTPROJ:  restage h in LDS, phase C MFMA out = h @ Wout + bout (fp32).
// ---------------------------------------------------------------------------
template <bool OUTPROJ>
__global__ __launch_bounds__(256) void fused_k(const unsigned short* __restrict__ xin,
                                               const unsigned char* __restrict__ x8,
                                               const unsigned int* __restrict__ pack,
                                               const int* __restrict__ cursor2,
                                               const short8* __restrict__ wp,
                                               const float* __restrict__ bias,
                                               unsigned short* __restrict__ xout,
                                               unsigned char* __restrict__ x8out,
                                               const short8* __restrict__ wpo,
                                               const float* __restrict__ bout,
                                               float* __restrict__ outp) {
    __shared__ unsigned int eraw[CAP2];
    __shared__ unsigned int ssrc[CAP2];
    __shared__ int nsh;
    __shared__ int bcnt[32];
    __shared__ int boff[33];
    __shared__ unsigned short mlds[PART_NODES][136];   // stride 272 B

    const int t = threadIdx.x;
    const int p = blockIdx.x;

    if (t == 0) {
        int c = cursor2[p] - (p << 10);
        nsh = (c < CAP2) ? c : CAP2;
    }
    if (t < 32) bcnt[t] = 0;
    __syncthreads();
    const int n = nsh;

    // stage slab + per-node histogram
    const unsigned int* gsrc = pack + ((size_t)p << 10);
    for (int i = t; i < n; i += 256) {
        unsigned int pk = gsrc[i];
        eraw[i] = pk;
        atomicAdd(&bcnt[pk >> 17], 1);
    }
    __syncthreads();

    if (t == 0) {
        int s = 0;
        #pragma unroll
        for (int i = 0; i < 32; ++i) { boff[i] = s; s += bcnt[i]; }
        boff[32] = s;
    }
    __syncthreads();
    if (t < 32) bcnt[t] = boff[t];             // reuse as cursor
    __syncthreads();

    for (int i = t; i < n; i += 256) {
        unsigned int pk = eraw[i];
        int pos = atomicAdd(&bcnt[pk >> 17], 1);
        ssrc[pos] = pk & 0x1ffffu;
    }
    __syncthreads();

    // ---- phase A: fp8 gather into mlds (8 edge-loads in flight) ----
    const int w = t >> 6, lane = t & 63;
    const int sub = lane >> 4;                 // edge slot 0..3
    const int cl = lane & 15;                  // column group (cols cl*8..+7)

    for (int g = 0; g < 8; ++g) {
        const int ni = w * 8 + g;
        const int b = boff[ni];
        const int eN = boff[ni + 1];

        float acc[8];
        #pragma unroll
        for (int r = 0; r < 8; ++r) acc[r] = 0.f;

        int i = b + sub;
        for (; i + 4 < eN; i += 8) {
            int s0 = ssrc[i];
            int s1 = ssrc[i + 4];
            uint2 u0 = *(const uint2*)(x8 + (size_t)s0 * 128 + cl * 8);
            uint2 u1 = *(const uint2*)(x8 + (size_t)s1 * 128 + cl * 8);
            f32x2 q;
            q = __builtin_amdgcn_cvt_pk_f32_fp8(u0.x, false); acc[0] += q[0]; acc[1] += q[1];
            q = __builtin_amdgcn_cvt_pk_f32_fp8(u0.x, true);  acc[2] += q[0]; acc[3] += q[1];
            q = __builtin_amdgcn_cvt_pk_f32_fp8(u0.y, false); acc[4] += q[0]; acc[5] += q[1];
            q = __builtin_amdgcn_cvt_pk_f32_fp8(u0.y, true);  acc[6] += q[0]; acc[7] += q[1];
            q = __builtin_amdgcn_cvt_pk_f32_fp8(u1.x, false); acc[0] += q[0]; acc[1] += q[1];
            q = __builtin_amdgcn_cvt_pk_f32_fp8(u1.x, true);  acc[2] += q[0]; acc[3] += q[1];
            q = __builtin_amdgcn_cvt_pk_f32_fp8(u1.y, false); acc[4] += q[0]; acc[5] += q[1];
            q = __builtin_amdgcn_cvt_pk_f32_fp8(u1.y, true);  acc[6] += q[0]; acc[7] += q[1];
        }
        if (i < eN) {
            int s0 = ssrc[i];
            uint2 u0 = *(const uint2*)(x8 + (size_t)s0 * 128 + cl * 8);
            f32x2 q;
            q = __builtin_amdgcn_cvt_pk_f32_fp8(u0.x, false); acc[0] += q[0]; acc[1] += q[1];
            q = __builtin_amdgcn_cvt_pk_f32_fp8(u0.x, true);  acc[2] += q[0]; acc[3] += q[1];
            q = __builtin_amdgcn_cvt_pk_f32_fp8(u0.y, false); acc[4] += q[0]; acc[5] += q[1];
            q = __builtin_amdgcn_cvt_pk_f32_fp8(u0.y, true);  acc[6] += q[0]; acc[7] += q[1];
        }
        #pragma unroll
        for (int r = 0; r < 8; ++r) {
            acc[r] += __shfl_xor(acc[r], 16);
            acc[r] += __shfl_xor(acc[r], 32);
        }
        float inv = 1.0f / fmaxf((float)(eN - b), 1.0f);
        float lo = acc[sub * 2 + 0] * inv;
        float hi = acc[sub * 2 + 1] * inv;
        unsigned int o = ((unsigned int)f2bf(hi) << 16) | (unsigned int)f2bf(lo);
        *(unsigned int*)(&mlds[ni][cl * 8 + sub * 2]) = o;
    }
    __syncthreads();

    // ---- phase B: 32-row GEMM, K=256 (self 0..127 global bf16, mean LDS) ----
    const int frag = w & 1;                    // 16-row fragment 0/1
    const int cg0 = (w >> 1) * 4;              // col-tile group base (of 8)
    const int r15 = lane & 15;
    const int khi = lane >> 4;                 // 0..3
    const int row0 = p * PART_NODES + frag * 16;
    const unsigned short* arow = xin + (size_t)(row0 + r15) * 128 + khi * 8;

    f32x4 acc[4];
    #pragma unroll
    for (int c = 0; c < 4; ++c) acc[c] = {0.f, 0.f, 0.f, 0.f};

    #pragma unroll
    for (int ks = 0; ks < 8; ++ks) {
        short8 a;
        if (ks < 4) a = *(const short8*)(arow + ks * 32);
        else        a = *(const short8*)(&mlds[frag * 16 + r15][(ks - 4) * 32 + khi * 8]);
        #pragma unroll
        for (int c = 0; c < 4; ++c) {
            short8 b = wp[(ks * 8 + cg0 + c) * 64 + lane];
            acc[c] = __builtin_amdgcn_mfma_f32_16x16x32_bf16(a, b, acc[c], 0, 0, 0);
        }
    }

    const int rhi = khi, col0 = r15;
    if (!OUTPROJ) {
        #pragma unroll
        for (int c = 0; c < 4; ++c) {
            float bv = bias[(cg0 + c) * 16 + col0];
            #pragma unroll
            for (int j = 0; j < 4; ++j) {
                float v = fmaxf(acc[c][j] + bv, 0.f);
                size_t off = (size_t)(row0 + rhi * 4 + j) * 128 + (cg0 + c) * 16 + col0;
                xout[off] = f2bf(v);
                x8out[off] = f2fp8(v);         // fp8 shadow for next layer
            }
        }
    } else {
        __syncthreads();                        // all mlds reads done
        // restage h tile (bias+relu) into mlds as bf16
        #pragma unroll
        for (int c = 0; c < 4; ++c) {
            float bv = bias[(cg0 + c) * 16 + col0];
            #pragma unroll
            for (int j = 0; j < 4; ++j) {
                float v = fmaxf(acc[c][j] + bv, 0.f);
                mlds[frag * 16 + rhi * 4 + j][(cg0 + c) * 16 + col0] = f2bf(v);
            }
        }
        __syncthreads();
        // ---- phase C: out[32 x 64] = h[32 x 128] @ Wout + bout ----
        const int frag2 = w & 1;
        const int ct0 = (w >> 1) * 2;          // 2 col-tiles of 4
        f32x4 oacc[2];
        oacc[0] = {0.f, 0.f, 0.f, 0.f};
        oacc[1] = {0.f, 0.f, 0.f, 0.f};
        #pragma unroll
        for (int ks = 0; ks < 4; ++ks) {
            short8 a = *(const short8*)(&mlds[frag2 * 16 + r15][ks * 32 + khi * 8]);
            #pragma unroll
            for (int c = 0; c < 2; ++c) {
                short8 b = wpo[(ks * 4 + ct0 + c) * 64 + lane];
                oacc[c] = __builtin_amdgcn_mfma_f32_16x16x32_bf16(a, b, oacc[c], 0, 0, 0);
            }
        }
        #pragma unroll
        for (int c = 0; c < 2; ++c) {
            float bv = bout[(ct0 + c) * 16 + col0];
            #pragma unroll
            for (int j = 0; j < 4; ++j) {
                outp[(size_t)(p * PART_NODES + frag2 * 16 + rhi * 4 + j) * N_CLASSES
                     + (ct0 + c) * 16 + col0] = oacc[c][j] + bv;
            }
        }
    }
}

// ---------------------------------------------------------------------------
extern "C" void kernel_launch(void* const* d_in, const int* in_sizes, int n_in,
                              void* d_out, int out_size, void* d_ws, size_t ws_size,
                              hipStream_t stream) {
    const float* feat   = (const float*)d_in[0];
    const int*   src    = (const int*)d_in[1];
    const int*   dst    = (const int*)d_in[2];
    const float* Wself1 = (const float*)d_in[3];
    const float* Wneigh1= (const float*)d_in[4];
    const float* b1     = (const float*)d_in[5];
    const float* Wself2 = (const float*)d_in[6];
    const float* Wneigh2= (const float*)d_in[7];
    const float* b2     = (const float*)d_in[8];
    const float* Wout   = (const float*)d_in[9];
    const float* bout   = (const float*)d_in[10];
    float* out = (float*)d_out;
    (void)ws_size;

    // workspace layout (~100 MB)
    int* cursor1 = (int*)d_ws;                                    // 49 (pad 64)
    int* cursor2 = cursor1 + 64;                                  // 3136
    unsigned int* pack1 = (unsigned int*)(cursor2 + NCTR2);       // 49*40960
    unsigned int* pack2 = pack1 + (size_t)NB1 * CAP1;             // 3136*1024
    unsigned short* fbuf1 = (unsigned short*)(pack2 + (size_t)NCTR2 * CAP2);
    unsigned short* h1    = fbuf1 + (size_t)N_NODES * D;          // N*128 bf16
    unsigned int* f8feat  = (unsigned int*)(h1 + (size_t)N_NODES * D);   // N*32
    unsigned int* h1f8    = f8feat + (size_t)N_NODES * (D / 4);          // N*32
    unsigned short* wp1   = (unsigned short*)(h1f8 + (size_t)N_NODES * (D / 4));
    unsigned short* wp2   = wp1 + 256 * 128;
    unsigned short* wpo   = wp2 + 256 * 128;                      // 128*64

    // ---- prep: cursor init ∥ cvt (bf16+fp8) ∥ weight pack ----
    prep_k<<<CIB + CVTB + PKB, 256, 0, stream>>>(cursor1, cursor2, feat,
                                                 fbuf1, f8feat,
                                                 Wself1, Wneigh1, Wself2, Wneigh2,
                                                 Wout, wp1, wp2, wpo);

    // ---- two-pass edge binning ----
    bin1_k<<<EB1, 256, 0, stream>>>(src, dst, cursor1, pack1);
    bin2_k<<<NB1 * SUBB, 256, 0, stream>>>(cursor1, cursor2, pack1, pack2);

    // ---- layer 1 (fused gather+GEMM, fp8 payload; writes h1 + fp8 shadow) ----
    fused_k<false><<<NPART, 256, 0, stream>>>(fbuf1, (const unsigned char*)f8feat,
                                              pack2, cursor2,
                                              (const short8*)wp1, b1, h1,
                                              (unsigned char*)h1f8,
                                              nullptr, nullptr, nullptr);

    // ---- layer 2 + output projection (fp8 payload) ----
    fused_k<true><<<NPART, 256, 0, stream>>>(h1, (const unsigned char*)h1f8,
                                             pack2, cursor2,
                                             (const short8*)wp2, b2, nullptr, nullptr,
                                             (const short8*)wpo, bout, out);
}